// Round 9
// baseline (2007.812 us; speedup 1.0000x reference)
//
#include <hip/hip_runtime.h>
#include <cstdint>
#include <cstddef>

#define S_  512
#define B_  32
#define D_  512
#define FF_ 2048
#define L_  6
#define O_  1000
#define M_  (B_*S_)     // 16384 rows of activations
#define G_  256         // attention groups (buggy reshape semantics)
#define DH_ 64

typedef __attribute__((ext_vector_type(8))) short bf16x8;
typedef __attribute__((ext_vector_type(4))) float f32x4;
typedef __attribute__((ext_vector_type(16))) float f32x16;

__device__ __forceinline__ unsigned short f2bf(float f) {
  unsigned int u = __builtin_bit_cast(unsigned int, f);
  u = (u + 0x7fffu + ((u >> 16) & 1u)) >> 16;
  return (unsigned short)u;
}
__device__ __forceinline__ float bf2f(unsigned short u) {
  return __builtin_bit_cast(float, (unsigned int)u << 16);
}
__device__ __forceinline__ unsigned int pkbf(float a, float b) {
  return (unsigned int)f2bf(a) | ((unsigned int)f2bf(b) << 16);
}
// truncating pack of 2 floats -> 2 bf16 in one v_perm_b32 (hi16 of each)
__device__ __forceinline__ unsigned int prm(float a, float b) {
  return __builtin_amdgcn_perm(__builtin_bit_cast(unsigned int, b),
                               __builtin_bit_cast(unsigned int, a), 0x07060302u);
}
__device__ __forceinline__ void gload_lds16(const void* g, void* l) {
  __builtin_amdgcn_global_load_lds(
      (const __attribute__((address_space(1))) unsigned int*)g,
      (__attribute__((address_space(3))) unsigned int*)l, 16, 0, 0);
}

// ---------------- positional encoding table [512][512] f32 ----------------
__global__ void pe_kernel(float* __restrict__ pe) {
  int i = blockIdx.x * 256 + threadIdx.x;
  int s = i >> 9, d = i & 511;
  double de = (double)(d & ~1);
  double ang = (double)s * exp(de * (-9.210340371976184 / 512.0));
  pe[i] = (d & 1) ? (float)cos(ang) : (float)sin(ang);
}

// ------------- transpose-convert W [z][K][N] f32 -> Wt [z-stride ozs][N][K] bf16 -------------
__global__ void wconv_kernel(const float* __restrict__ W, unsigned short* __restrict__ Wt,
                             int K, int N, size_t ozs) {
  __shared__ float tile[32][33];
  const float* Wl = W + (size_t)blockIdx.z * K * N;
  unsigned short* Wtl = Wt + (size_t)blockIdx.z * ozs;
  int k0 = blockIdx.x * 32, n0 = blockIdx.y * 32;
  int c = threadIdx.x & 31, rb = threadIdx.x >> 5;
#pragma unroll
  for (int i = 0; i < 4; ++i) {
    int r = rb + i * 8;
    tile[r][c] = Wl[(size_t)(k0 + r) * N + n0 + c];
  }
  __syncthreads();
#pragma unroll
  for (int i = 0; i < 4; ++i) {
    int r = rb + i * 8;
    Wtl[(size_t)(n0 + r) * K + k0 + c] = f2bf(tile[c][r]);
  }
}

// ------------- embedding + PE (bf16 out only) -------------
__global__ void embed_kernel(const int* __restrict__ x, const float* __restrict__ emb,
                             const float* __restrict__ pe, unsigned short* __restrict__ xb) {
  int bi = blockIdx.x;            // s*B + b
  int s = bi / B_, b = bi % B_;
  int tok = x[s * B_ + b];
  int d = threadIdx.x * 4;
  float4 e = *(const float4*)(emb + (size_t)tok * D_ + d);
  float4 p = *(const float4*)(pe + (size_t)s * D_ + d);
  size_t o = ((size_t)b * S_ + s) * D_ + d;
  ushort4 u;
  u.x = f2bf(e.x + p.x); u.y = f2bf(e.y + p.y);
  u.z = f2bf(e.z + p.z); u.w = f2bf(e.w + p.w);
  *(ushort4*)(xb + o) = u;
}

// ------------- bf16 MFMA GEMM, 128(M)x256(N) tile, BK=32, 4 waves (each 128Mx64N) -------------
// kspl>1: split-K, each wg does K/kspl, writes f32 partials (no bias) to pout[kq][M][N]
__global__ __launch_bounds__(256, 2) void gemm_kernel(
    const unsigned short* __restrict__ A, const unsigned short* __restrict__ Bt,
    const float* __restrict__ b0, const float* __restrict__ b1, const float* __restrict__ b2,
    unsigned short* __restrict__ o0, unsigned short* __restrict__ o1, unsigned short* __restrict__ o2,
    float* __restrict__ pout,
    int K, int N, int relu, int split, int nbx, int kspl) {
  __shared__ unsigned short As[3][128 * 32];   // 8 KB each
  __shared__ unsigned short Bs[3][256 * 32];   // 16 KB each -> 72 KB total, 2 wg/CU
  int nwg = nbx * (M_ / 128) * kspl;
  int cpx = nwg >> 3;
  int id = blockIdx.x;
  int wg = (id & 7) * cpx + (id >> 3);         // bijective: nwg % 8 == 0 for all launches
  int kq = wg % kspl; wg /= kspl;
  int bx = wg % nbx, by = wg / nbx;
  int m0 = by * 128, n0 = bx * 256;
  int Ks = K / kspl;

  int tid = threadIdx.x, lane = tid & 63, wid = tid >> 6;   // wid 0..3
  f32x4 acc[8][4];
#pragma unroll
  for (int mi = 0; mi < 8; ++mi)
#pragma unroll
    for (int ni = 0; ni < 4; ++ni) acc[mi][ni] = (f32x4)0.0f;

  int srow = lane >> 2, scol = (lane & 3) * 8;
  const unsigned short* Abase = A + (size_t)m0 * K + kq * Ks;
  const unsigned short* Bbase = Bt + (size_t)n0 * K + kq * Ks;
  int c16 = lane & 15, hi = lane >> 4;
  int koff = hi * 8;
  int brow = wid * 64 + c16;
  int nk = Ks >> 5;   // >= 3 for all our K

  auto STAGE = [&](int kt, int bb) {
    int k0 = kt * 32;
#pragma unroll
    for (int i = 0; i < 6; ++i) {
      int c = wid * 6 + i;
      if (c < 8) {
        gload_lds16(Abase + (size_t)(c * 16 + srow) * K + k0 + scol, (char*)As[bb] + c * 1024);
      } else {
        int c2 = c - 8;
        gload_lds16(Bbase + (size_t)(c2 * 16 + srow) * K + k0 + scol, (char*)Bs[bb] + c2 * 1024);
      }
    }
  };

  STAGE(0, 0); STAGE(1, 1); STAGE(2, 2);
  int bb = 0;
  for (int kt = 0; kt < nk; ++kt) {
    int rem = nk - 1 - kt;
    if (rem >= 2)      asm volatile("s_waitcnt vmcnt(12)" ::: "memory");
    else if (rem == 1) asm volatile("s_waitcnt vmcnt(6)" ::: "memory");
    else               asm volatile("s_waitcnt vmcnt(0)" ::: "memory");
    __builtin_amdgcn_s_barrier();       // tile kt visible to all waves
    __builtin_amdgcn_sched_barrier(0);
    bf16x8 af[8], bfr[4];
#pragma unroll
    for (int mi = 0; mi < 8; ++mi) af[mi] = *(const bf16x8*)&As[bb][(mi * 16 + c16) * 32 + koff];
#pragma unroll
    for (int ni = 0; ni < 4; ++ni) bfr[ni] = *(const bf16x8*)&Bs[bb][(brow + ni * 16) * 32 + koff];
    __builtin_amdgcn_s_setprio(1);
#pragma unroll
    for (int mi = 0; mi < 8; ++mi)
#pragma unroll
      for (int ni = 0; ni < 4; ++ni)
        acc[mi][ni] = __builtin_amdgcn_mfma_f32_16x16x32_bf16(bfr[ni], af[mi], acc[mi][ni], 0, 0, 0);
    __builtin_amdgcn_s_setprio(0);
    __builtin_amdgcn_sched_barrier(0);
    __builtin_amdgcn_s_barrier();       // all waves done reading buf bb
    if (kt + 3 < nk) STAGE(kt + 3, bb);
    bb = (bb == 2) ? 0 : bb + 1;
  }

  if (pout) {
    // split-K partial: f32, no bias
#pragma unroll
    for (int ni = 0; ni < 4; ++ni) {
      int colb = n0 + wid * 64 + ni * 16 + hi * 4;
#pragma unroll
      for (int mi = 0; mi < 8; ++mi) {
        int row = m0 + mi * 16 + c16;
        *(f32x4*)(pout + ((size_t)kq * M_ + row) * N + colb) = acc[mi][ni];
      }
    }
    return;
  }

  const float* bias = b0;
  unsigned short* outb = o0;
  int nbase = n0, ostride = N;
  if (split) {                          // 256-tile lies in exactly one 512-col segment
    int seg = n0 >> 9;
    if (seg == 1) { bias = b1; outb = o1; }
    else if (seg == 2) { bias = b2; outb = o2; }
    nbase = n0 & 511; ostride = 512;
  }
  // swapped layout: lane holds row = mi*16+c16, cols = wid*64+ni*16+hi*4+{0..3}
#pragma unroll
  for (int ni = 0; ni < 4; ++ni) {
    int colb = nbase + wid * 64 + ni * 16 + hi * 4;
    float4 bv = *(const float4*)(bias + colb);
#pragma unroll
    for (int mi = 0; mi < 8; ++mi) {
      int row = m0 + mi * 16 + c16;
      float v0 = acc[mi][ni][0] + bv.x;
      float v1 = acc[mi][ni][1] + bv.y;
      float v2 = acc[mi][ni][2] + bv.z;
      float v3 = acc[mi][ni][3] + bv.w;
      if (relu) { v0 = fmaxf(v0, 0.f); v1 = fmaxf(v1, 0.f); v2 = fmaxf(v2, 0.f); v3 = fmaxf(v3, 0.f); }
      *(uint2*)(outb + (size_t)row * ostride + colb) = make_uint2(pkbf(v0, v1), pkbf(v2, v3));
    }
  }
}

// ------------- fused split-K reduce + bias + bf16-residual + LayerNorm -------------
__global__ __launch_bounds__(128) void addln2_kernel(
    const float* __restrict__ P, const unsigned short* __restrict__ R,
    const float* __restrict__ bias,
    const float* __restrict__ gamma, const float* __restrict__ beta,
    unsigned short* __restrict__ Out) {
  __shared__ float red[2], red2[2];
  int row = blockIdx.x, t = threadIdx.x;
  size_t o = (size_t)row * 512 + t * 4;
  float4 p0 = *(const float4*)(P + o);
  float4 p1 = *(const float4*)(P + (size_t)M_ * 512 + o);
  float4 bv = *(const float4*)(bias + t * 4);
  ushort4 rv = *(const ushort4*)(R + o);
  float v0 = p0.x + p1.x + bv.x + bf2f(rv.x);
  float v1 = p0.y + p1.y + bv.y + bf2f(rv.y);
  float v2 = p0.z + p1.z + bv.z + bf2f(rv.z);
  float v3 = p0.w + p1.w + bv.w + bf2f(rv.w);
  float s = v0 + v1 + v2 + v3;
#pragma unroll
  for (int m = 1; m < 64; m <<= 1) s += __shfl_xor(s, m);
  if ((t & 63) == 0) red[t >> 6] = s;
  __syncthreads();
  float mean = (red[0] + red[1]) * (1.0f / 512.0f);
  float d0 = v0 - mean, d1 = v1 - mean, d2 = v2 - mean, d3 = v3 - mean;
  float sq = d0 * d0 + d1 * d1 + d2 * d2 + d3 * d3;
#pragma unroll
  for (int m = 1; m < 64; m <<= 1) sq += __shfl_xor(sq, m);
  if ((t & 63) == 0) red2[t >> 6] = sq;
  __syncthreads();
  float var = (red2[0] + red2[1]) * (1.0f / 512.0f);
  float rstd = rsqrtf(var + 1e-5f);
  float4 gg = *(const float4*)(gamma + t * 4);
  float4 bb = *(const float4*)(beta + t * 4);
  float y0 = d0 * rstd * gg.x + bb.x;
  float y1 = d1 * rstd * gg.y + bb.y;
  float y2 = d2 * rstd * gg.z + bb.z;
  float y3 = d3 * rstd * gg.w + bb.w;
  *(uint2*)(Out + o) = make_uint2(pkbf(y0, y1), pkbf(y2, y3));
}

// ------------- flash attention, 32x32 swapped-QK^T, in-register softmax -------------
// grid (2, 256): wave owns 64 q rows (two 32-row sub-blocks)
__global__ __launch_bounds__(256) void attn_kernel(
    const unsigned short* __restrict__ Q, const unsigned short* __restrict__ Kb,
    const unsigned short* __restrict__ Vb, unsigned short* __restrict__ Ctx) {
  __shared__ char KlB[8192];   // K tile [64 k][64 d] bf16, XOR-swizzled rows
  __shared__ char VtB[8192];   // V^T tile [64 d][64 k] bf16, XOR-swizzled rows
  int g = blockIdx.y;
  int q0 = blockIdx.x * 256;
  const unsigned short* Kg = Kb + (size_t)g * 512 * 64;
  const unsigned short* Vg = Vb + (size_t)g * 512 * 64;
  int tid = threadIdx.x, lane = tid & 63, wid = tid >> 6;
  int l31 = lane & 31, h = lane >> 5;
  bool lo = (lane < 32);
  int qrowA = q0 + wid * 64 + l31;
  int qrowB = qrowA + 32;
  const float sc2 = 0.125f * 1.44269504f;

  bf16x8 qfa[4], qfb[4];
  {
    const unsigned short* qpa = Q + ((size_t)g * 512 + qrowA) * 64;
    const unsigned short* qpb = Q + ((size_t)g * 512 + qrowB) * 64;
#pragma unroll
    for (int c = 0; c < 4; ++c) {
      bf16x8 ra = *(const bf16x8*)(qpa + c * 16 + h * 8);
      bf16x8 rb = *(const bf16x8*)(qpb + c * 16 + h * 8);
      union { unsigned int u[4]; bf16x8 v; } ua, ub;
#pragma unroll
      for (int j = 0; j < 4; ++j) {
        ua.u[j] = pkbf(bf2f((unsigned short)ra[2 * j]) * sc2,
                       bf2f((unsigned short)ra[2 * j + 1]) * sc2);
        ub.u[j] = pkbf(bf2f((unsigned short)rb[2 * j]) * sc2,
                       bf2f((unsigned short)rb[2 * j + 1]) * sc2);
      }
      qfa[c] = ua.v; qfb[c] = ub.v;
    }
  }

  f32x16 cA0 = (f32x16)0.0f, cA1 = (f32x16)0.0f;   // O^T halves, sub-block A
  f32x16 cB0 = (f32x16)0.0f, cB1 = (f32x16)0.0f;   // sub-block B
  float mrA = -3.0e38f, lsA = 0.0f;
  float mrB = -3.0e38f, lsB = 0.0f;

  for (int kt = 0; kt < 8; ++kt) {
    __syncthreads();
    {
      int row = tid >> 2;
      size_t base = (size_t)(kt * 64 + row) * 64;
#pragma unroll
      for (int i = 0; i < 2; ++i) {
        int cb = ((tid & 3) + 4 * i) * 16;       // byte col within 128B row
        bf16x8 kv = *(const bf16x8*)(Kg + base + cb / 2);
        *(bf16x8*)(KlB + row * 128 + (cb ^ ((row & 7) << 4))) = kv;
        bf16x8 vv = *(const bf16x8*)(Vg + base + cb / 2);
#pragma unroll
        for (int j = 0; j < 8; ++j) {
          int d = cb / 2 + j;
          *(unsigned short*)(VtB + d * 128 + ((2 * row) ^ ((d & 7) << 4))) =
              (unsigned short)vv[j];
        }
      }
    }
    __syncthreads();

#pragma unroll
    for (int sub = 0; sub < 2; ++sub) {
      f32x16 s0 = (f32x16)0.0f, s1 = (f32x16)0.0f;
#pragma unroll
      for (int c = 0; c < 4; ++c) {
        int cb = 32 * c + 16 * h;
        int sw = cb ^ ((l31 & 7) << 4);
        bf16x8 k0 = *(const bf16x8*)(KlB + l31 * 128 + sw);
        bf16x8 k1 = *(const bf16x8*)(KlB + (32 + l31) * 128 + sw);
        bf16x8 qf = sub ? qfb[c] : qfa[c];
        s0 = __builtin_amdgcn_mfma_f32_32x32x16_bf16(k0, qf, s0, 0, 0, 0);
        s1 = __builtin_amdgcn_mfma_f32_32x32x16_bf16(k1, qf, s1, 0, 0, 0);
      }

      float mr = sub ? mrB : mrA;
      float ls = sub ? lsB : lsA;
      float pm = s0[0];
#pragma unroll
      for (int i = 1; i < 16; ++i) pm = fmaxf(pm, s0[i]);
#pragma unroll
      for (int i = 0; i < 16; ++i) pm = fmaxf(pm, s1[i]);
      pm = fmaxf(pm, __shfl_xor(pm, 32));
      // T13 defer-max: skip O-rescale while tile max stays within 2^8 of running max
      if (!__all(pm <= mr + 8.0f)) {
        float mnew = fmaxf(mr, pm);
        float alpha = exp2f(mr - mnew);
        ls *= alpha;
        if (sub) {
#pragma unroll
          for (int i = 0; i < 16; ++i) { cB0[i] *= alpha; cB1[i] *= alpha; }
        } else {
#pragma unroll
          for (int i = 0; i < 16; ++i) { cA0[i] *= alpha; cA1[i] *= alpha; }
        }
        mr = mnew;
      }
      float p[32];
      float rs = 0.0f;
#pragma unroll
      for (int i = 0; i < 16; ++i) { p[i] = exp2f(s0[i] - mr); rs += p[i]; }
#pragma unroll
      for (int i = 0; i < 16; ++i) { p[16 + i] = exp2f(s1[i] - mr); rs += p[16 + i]; }
      float rso = __shfl_xor(rs, 32);
      ls += rs + rso;
      if (sub) { mrB = mr; lsB = ls; } else { mrA = mr; lsA = ls; }

      union { unsigned int u[4]; bf16x8 v; } pa[4];
#pragma unroll
      for (int t = 0; t < 2; ++t) {
#pragma unroll
        for (int u = 0; u < 2; ++u) {
#pragma unroll
          for (int pr = 0; pr < 2; ++pr) {
            const int b0i = t * 16 + 8 * u;
            unsigned int a  = prm(p[b0i + 2 * pr],     p[b0i + 2 * pr + 1]);
            unsigned int b  = prm(p[b0i + 4 + 2 * pr], p[b0i + 4 + 2 * pr + 1]);
            unsigned int sa = __shfl_xor(a, 32);
            unsigned int sb = __shfl_xor(b, 32);
            pa[t * 2 + u].u[pr]     = lo ? a  : sb;
            pa[t * 2 + u].u[2 + pr] = lo ? sa : b;
          }
        }
      }

#pragma unroll
      for (int kc = 0; kc < 4; ++kc) {
        int cb = 32 * kc + 16 * h;
        int sw = cb ^ ((l31 & 7) << 4);
        bf16x8 v0 = *(const bf16x8*)(VtB + l31 * 128 + sw);
        bf16x8 v1 = *(const bf16x8*)(VtB + (32 + l31) * 128 + sw);
        if (sub) {
          cB0 = __builtin_amdgcn_mfma_f32_32x32x16_bf16(v0, pa[kc].v, cB0, 0, 0, 0);
          cB1 = __builtin_amdgcn_mfma_f32_32x32x16_bf16(v1, pa[kc].v, cB1, 0, 0, 0);
        } else {
          cA0 = __builtin_amdgcn_mfma_f32_32x32x16_bf16(v0, pa[kc].v, cA0, 0, 0, 0);
          cA1 = __builtin_amdgcn_mfma_f32_32x32x16_bf16(v1, pa[kc].v, cA1, 0, 0, 0);
        }
      }
    }
  }

#pragma unroll
  for (int sub = 0; sub < 2; ++sub) {
    float inv = 1.0f / (sub ? lsB : lsA);
    int qrow = sub ? qrowB : qrowA;
    unsigned short* cp = Ctx + ((size_t)g * 512 + qrow) * 64;
#pragma unroll
    for (int dh = 0; dh < 2; ++dh) {
#pragma unroll
      for (int rq = 0; rq < 4; ++rq) {
        float e0 = (sub ? (dh ? cB1[rq * 4 + 0] : cB0[rq * 4 + 0]) : (dh ? cA1[rq * 4 + 0] : cA0[rq * 4 + 0])) * inv;
        float e1 = (sub ? (dh ? cB1[rq * 4 + 1] : cB0[rq * 4 + 1]) : (dh ? cA1[rq * 4 + 1] : cA0[rq * 4 + 1])) * inv;
        float e2 = (sub ? (dh ? cB1[rq * 4 + 2] : cB0[rq * 4 + 2]) : (dh ? cA1[rq * 4 + 2] : cA0[rq * 4 + 2])) * inv;
        float e3 = (sub ? (dh ? cB1[rq * 4 + 3] : cB0[rq * 4 + 3]) : (dh ? cA1[rq * 4 + 3] : cA0[rq * 4 + 3])) * inv;
        int d0 = dh * 32 + rq * 8 + h * 4;
        *(uint2*)(cp + d0) = make_uint2(pkbf(e0, e1), pkbf(e2, e3));
      }
    }
  }
}

// ------------- final FC: out[32][1000] = act[32][262144](bf16) @ Wfc + bfc (split-K) -------------
// 512 threads, thread t owns cols {t, t+512}; 4 k per inner iter; FMA/HBM-bound
#define KCH 1024
__global__ __launch_bounds__(512) void fc_part_kernel(const unsigned short* __restrict__ act,
                                                      const float* __restrict__ Wfc,
                                                      float* __restrict__ part) {
  __shared__ float al[32][256];
  int t = threadIdx.x;
  int kc = blockIdx.x;
  size_t k0 = (size_t)kc * KCH;
  int o1 = t;               // < 1000 always
  int o2 = 512 + t;
  bool a2 = (o2 < O_);
  float acc1[32], acc2[32];
#pragma unroll
  for (int bb = 0; bb < 32; ++bb) { acc1[bb] = 0.0f; acc2[bb] = 0.0f; }
  for (int sub = 0; sub < KCH / 256; ++sub) {
    __syncthreads();
    for (int i = t; i < 32 * 128; i += 512) {
      int bb = i >> 7, kk = (i & 127) * 2;
      ushort2 u = *(const ushort2*)(act + (size_t)bb * 262144 + k0 + sub * 256 + kk);
      al[bb][kk] = bf2f(u.x);
      al[bb][kk + 1] = bf2f(u.y);
    }
    __syncthreads();
    const float* wp = Wfc + (k0 + sub * 256) * O_;
    for (int kk = 0; kk < 256; kk += 4) {
      const float* wr = wp + (size_t)kk * O_;
      float w10 = wr[o1];
      float w11 = wr[O_ + o1];
      float w12 = wr[2 * O_ + o1];
      float w13 = wr[3 * O_ + o1];
      float w20 = a2 ? wr[o2] : 0.0f;
      float w21 = a2 ? wr[O_ + o2] : 0.0f;
      float w22 = a2 ? wr[2 * O_ + o2] : 0.0f;
      float w23 = a2 ? wr[3 * O_ + o2] : 0.0f;
#pragma unroll
      for (int bb = 0; bb < 32; ++bb) {
        f32x4 av = *(const f32x4*)&al[bb][kk];
        acc1[bb] = fmaf(av[0], w10, acc1[bb]);
        acc1[bb] = fmaf(av[1], w11, acc1[bb]);
        acc1[bb] = fmaf(av[2], w12, acc1[bb]);
        acc1[bb] = fmaf(av[3], w13, acc1[bb]);
        acc2[bb] = fmaf(av[0], w20, acc2[bb]);
        acc2[bb] = fmaf(av[1], w21, acc2[bb]);
        acc2[bb] = fmaf(av[2], w22, acc2[bb]);
        acc2[bb] = fmaf(av[3], w23, acc2[bb]);
      }
    }
  }
#pragma unroll
  for (int bb = 0; bb < 32; ++bb) {
    part[((size_t)kc * 32 + bb) * O_ + o1] = acc1[bb];
    if (a2) part[((size_t)kc * 32 + bb) * O_ + o2] = acc2[bb];
  }
}

__global__ void fc_reduce_kernel(const float* __restrict__ part, const float* __restrict__ bfc,
                                 float* __restrict__ out) {
  int o = blockIdx.x * 256 + threadIdx.x;
  int b = blockIdx.y;
  if (o >= O_) return;
  float s = bfc[o];
  for (int c = 0; c < 256; ++c) s += part[((size_t)c * 32 + b) * O_ + o];
  out[(size_t)b * O_ + o] = s;
}

extern "C" void kernel_launch(void* const* d_in, const int* in_sizes, int n_in,
                              void* d_out, int out_size, void* d_ws, size_t ws_size,
                              hipStream_t stream) {
  const int*   x   = (const int*)d_in[0];
  const float* emb = (const float*)d_in[2];
  const float* Wq  = (const float*)d_in[3];
  const float* bq  = (const float*)d_in[4];
  const float* Wk  = (const float*)d_in[5];
  const float* bk  = (const float*)d_in[6];
  const float* Wv  = (const float*)d_in[7];
  const float* bv  = (const float*)d_in[8];
  const float* Wo  = (const float*)d_in[9];
  const float* bo  = (const float*)d_in[10];
  const float* g1  = (const float*)d_in[11];
  const float* bn1 = (const float*)d_in[12];
  const float* W1  = (const float*)d_in[13];
  const float* bf1 = (const float*)d_in[14];
  const float* W2  = (const float*)d_in[15];
  const float* bf2 = (const float*)d_in[16];
  const float* g2  = (const float*)d_in[17];
  const float* bn2 = (const float*)d_in[18];
  const float* Wfc = (const float*)d_in[19];
  const float* bfc = (const float*)d_in[20];
  float* out = (float*)d_out;

  char* ws = (char*)d_ws;
  size_t off = 0;
  auto take = [&](size_t bytes) { char* p = ws + off; off += (bytes + 255) & ~(size_t)255; return p; };
  float*          pe   = (float*)take((size_t)512 * 512 * 4);
  unsigned short* wqkv = (unsigned short*)take((size_t)L_ * 1536 * 512 * 2);
  unsigned short* wot  = (unsigned short*)take((size_t)L_ * 512 * 512 * 2);
  unsigned short* w1t  = (unsigned short*)take((size_t)L_ * 2048 * 512 * 2);
  unsigned short* w2t  = (unsigned short*)take((size_t)L_ * 512 * 2048 * 2);
  unsigned short* xb   = (unsigned short*)take((size_t)M_ * 512 * 2);
  unsigned short* qb   = (unsigned short*)take((size_t)M_ * 512 * 2);
  unsigned short* kb   = (unsigned short*)take((size_t)M_ * 512 * 2);
  unsigned short* vb   = (unsigned short*)take((size_t)M_ * 512 * 2);
  unsigned short* cxb  = (unsigned short*)take((size_t)M_ * 512 * 2);
  unsigned short* hb   = (unsigned short*)take((size_t)M_ * 512 * 2);
  float*          pf   = (float*)take((size_t)2 * M_ * 512 * 4);   // split-K partials
  unsigned short* f1b  = qb;          // alias: q/k/v/cxb region (67 MB contiguous) free during FFN
  float*          part = (float*)qb;  // alias: free after last layer (needs 32.8 MB)

  pe_kernel<<<1024, 256, 0, stream>>>(pe);
  wconv_kernel<<<dim3(16, 16, L_), 256, 0, stream>>>(Wq, wqkv,          512, 512,  (size_t)1536 * 512);
  wconv_kernel<<<dim3(16, 16, L_), 256, 0, stream>>>(Wk, wqkv + 262144, 512, 512,  (size_t)1536 * 512);
  wconv_kernel<<<dim3(16, 16, L_), 256, 0, stream>>>(Wv, wqkv + 524288, 512, 512,  (size_t)1536 * 512);
  wconv_kernel<<<dim3(16, 16, L_), 256, 0, stream>>>(Wo, wot,           512, 512,  (size_t)512 * 512);
  wconv_kernel<<<dim3(16, 64, L_), 256, 0, stream>>>(W1, w1t,           512, 2048, (size_t)2048 * 512);
  wconv_kernel<<<dim3(64, 16, L_), 256, 0, stream>>>(W2, w2t,           2048, 512, (size_t)512 * 2048);
  embed_kernel<<<M_, 128, 0, stream>>>(x, emb, pe, xb);

  for (int l = 0; l < L_; ++l) {
    // QKV: N=1536 -> nbx=6, grid 768
    gemm_kernel<<<768, 256, 0, stream>>>(
        xb, wqkv + (size_t)l * 1536 * 512,
        bq + l * 512, bk + l * 512, bv + l * 512,
        qb, kb, vb, nullptr, 512, 1536, 0, 1, 6, 1);
    attn_kernel<<<dim3(2, G_), 256, 0, stream>>>(qb, kb, vb, cxb);
    // O-proj: N=512, split-K 2 -> grid 512, f32 partials
    gemm_kernel<<<512, 256, 0, stream>>>(
        cxb, wot + (size_t)l * 512 * 512,
        nullptr, nullptr, nullptr,
        nullptr, nullptr, nullptr, pf, 512, 512, 0, 0, 2, 2);
    addln2_kernel<<<M_, 128, 0, stream>>>(pf, xb, bo + l * 512, g1 + l * 512, bn1 + l * 512, hb);
    // FF1: N=2048 -> nbx=8, grid 1024
    gemm_kernel<<<1024, 256, 0, stream>>>(
        hb, w1t + (size_t)l * 2048 * 512,
        bf1 + l * 2048, nullptr, nullptr,
        f1b, nullptr, nullptr, nullptr, 512, 2048, 1, 0, 8, 1);
    // FF2: N=512, K=2048, split-K 2 -> grid 512, f32 partials
    gemm_kernel<<<512, 256, 0, stream>>>(
        f1b, w2t + (size_t)l * 512 * 2048,
        nullptr, nullptr, nullptr,
        nullptr, nullptr, nullptr, pf, 2048, 512, 0, 0, 2, 2);
    addln2_kernel<<<M_, 128, 0, stream>>>(pf, hb, bf2 + l * 512, g2 + l * 512, bn2 + l * 512, xb);
  }

  fc_part_kernel<<<256, 512, 0, stream>>>(xb, Wfc, part);
  fc_reduce_kernel<<<dim3(4, 32), 256, 0, stream>>>(part, bfc, out);
}

// Round 10
// 1915.307 us; speedup vs baseline: 1.0483x; 1.0483x over previous
//
#include <hip/hip_runtime.h>
#include <cstdint>
#include <cstddef>

#define S_  512
#define B_  32
#define D_  512
#define FF_ 2048
#define L_  6
#define O_  1000
#define M_  (B_*S_)     // 16384 rows of activations
#define G_  256         // attention groups (buggy reshape semantics)
#define DH_ 64

typedef __attribute__((ext_vector_type(8))) short bf16x8;
typedef __attribute__((ext_vector_type(4))) float f32x4;
typedef __attribute__((ext_vector_type(16))) float f32x16;

__device__ __forceinline__ unsigned short f2bf(float f) {
  unsigned int u = __builtin_bit_cast(unsigned int, f);
  u = (u + 0x7fffu + ((u >> 16) & 1u)) >> 16;
  return (unsigned short)u;
}
__device__ __forceinline__ float bf2f(unsigned short u) {
  return __builtin_bit_cast(float, (unsigned int)u << 16);
}
__device__ __forceinline__ unsigned int pkbf(float a, float b) {
  return (unsigned int)f2bf(a) | ((unsigned int)f2bf(b) << 16);
}
// truncating pack of 2 floats -> 2 bf16 in one v_perm_b32 (hi16 of each)
__device__ __forceinline__ unsigned int prm(float a, float b) {
  return __builtin_amdgcn_perm(__builtin_bit_cast(unsigned int, b),
                               __builtin_bit_cast(unsigned int, a), 0x07060302u);
}
__device__ __forceinline__ void gload_lds16(const void* g, void* l) {
  __builtin_amdgcn_global_load_lds(
      (const __attribute__((address_space(1))) unsigned int*)g,
      (__attribute__((address_space(3))) unsigned int*)l, 16, 0, 0);
}

// ---------------- positional encoding table [512][512] f32 ----------------
__global__ void pe_kernel(float* __restrict__ pe) {
  int i = blockIdx.x * 256 + threadIdx.x;
  int s = i >> 9, d = i & 511;
  double de = (double)(d & ~1);
  double ang = (double)s * exp(de * (-9.210340371976184 / 512.0));
  pe[i] = (d & 1) ? (float)cos(ang) : (float)sin(ang);
}

// ------------- transpose-convert W [z][K][N] f32 -> Wt [z-stride ozs][N][K] bf16 -------------
__global__ void wconv_kernel(const float* __restrict__ W, unsigned short* __restrict__ Wt,
                             int K, int N, size_t ozs) {
  __shared__ float tile[32][33];
  const float* Wl = W + (size_t)blockIdx.z * K * N;
  unsigned short* Wtl = Wt + (size_t)blockIdx.z * ozs;
  int k0 = blockIdx.x * 32, n0 = blockIdx.y * 32;
  int c = threadIdx.x & 31, rb = threadIdx.x >> 5;
#pragma unroll
  for (int i = 0; i < 4; ++i) {
    int r = rb + i * 8;
    tile[r][c] = Wl[(size_t)(k0 + r) * N + n0 + c];
  }
  __syncthreads();
#pragma unroll
  for (int i = 0; i < 4; ++i) {
    int r = rb + i * 8;
    Wtl[(size_t)(n0 + r) * K + k0 + c] = f2bf(tile[c][r]);
  }
}

// ------------- embedding + PE (bf16 out only) -------------
__global__ void embed_kernel(const int* __restrict__ x, const float* __restrict__ emb,
                             const float* __restrict__ pe, unsigned short* __restrict__ xb) {
  int bi = blockIdx.x;            // s*B + b
  int s = bi / B_, b = bi % B_;
  int tok = x[s * B_ + b];
  int d = threadIdx.x * 4;
  float4 e = *(const float4*)(emb + (size_t)tok * D_ + d);
  float4 p = *(const float4*)(pe + (size_t)s * D_ + d);
  size_t o = ((size_t)b * S_ + s) * D_ + d;
  ushort4 u;
  u.x = f2bf(e.x + p.x); u.y = f2bf(e.y + p.y);
  u.z = f2bf(e.z + p.z); u.w = f2bf(e.w + p.w);
  *(ushort4*)(xb + o) = u;
}

// ------------- bf16 MFMA GEMM, 128(M)x256(N) tile, BK=32, 4 waves (each 128Mx64N) -------------
__global__ __launch_bounds__(256, 2) void gemm_kernel(
    const unsigned short* __restrict__ A, const unsigned short* __restrict__ Bt,
    const float* __restrict__ b0, const float* __restrict__ b1, const float* __restrict__ b2,
    unsigned short* __restrict__ o0, unsigned short* __restrict__ o1, unsigned short* __restrict__ o2,
    int K, int N, int relu, int split, int nbx) {
  __shared__ unsigned short As[3][128 * 32];   // 8 KB each
  __shared__ unsigned short Bs[3][256 * 32];   // 16 KB each -> 72 KB total, 2 wg/CU
  int nwg = nbx * (M_ / 128);
  int cpx = nwg >> 3;
  int id = blockIdx.x;
  int wg = (id & 7) * cpx + (id >> 3);         // bijective: nwg % 8 == 0 for all launches
  int bx = wg % nbx, by = wg / nbx;
  int m0 = by * 128, n0 = bx * 256;

  int tid = threadIdx.x, lane = tid & 63, wid = tid >> 6;   // wid 0..3
  f32x4 acc[8][4];
#pragma unroll
  for (int mi = 0; mi < 8; ++mi)
#pragma unroll
    for (int ni = 0; ni < 4; ++ni) acc[mi][ni] = (f32x4)0.0f;

  int srow = lane >> 2, scol = (lane & 3) * 8;
  const unsigned short* Abase = A + (size_t)m0 * K;
  const unsigned short* Bbase = Bt + (size_t)n0 * K;
  int c16 = lane & 15, hi = lane >> 4;
  int koff = hi * 8;
  int brow = wid * 64 + c16;
  int nk = K >> 5;

  auto STAGE = [&](int kt, int bb) {
    int k0 = kt * 32;
#pragma unroll
    for (int i = 0; i < 6; ++i) {
      int c = wid * 6 + i;
      if (c < 8) {
        gload_lds16(Abase + (size_t)(c * 16 + srow) * K + k0 + scol, (char*)As[bb] + c * 1024);
      } else {
        int c2 = c - 8;
        gload_lds16(Bbase + (size_t)(c2 * 16 + srow) * K + k0 + scol, (char*)Bs[bb] + c2 * 1024);
      }
    }
  };

  STAGE(0, 0); STAGE(1, 1); STAGE(2, 2);
  int bb = 0;
  for (int kt = 0; kt < nk; ++kt) {
    int rem = nk - 1 - kt;
    if (rem >= 2)      asm volatile("s_waitcnt vmcnt(12)" ::: "memory");
    else if (rem == 1) asm volatile("s_waitcnt vmcnt(6)" ::: "memory");
    else               asm volatile("s_waitcnt vmcnt(0)" ::: "memory");
    __builtin_amdgcn_s_barrier();
    __builtin_amdgcn_sched_barrier(0);
    bf16x8 af[8], bfr[4];
#pragma unroll
    for (int mi = 0; mi < 8; ++mi) af[mi] = *(const bf16x8*)&As[bb][(mi * 16 + c16) * 32 + koff];
#pragma unroll
    for (int ni = 0; ni < 4; ++ni) bfr[ni] = *(const bf16x8*)&Bs[bb][(brow + ni * 16) * 32 + koff];
    __builtin_amdgcn_s_setprio(1);
#pragma unroll
    for (int mi = 0; mi < 8; ++mi)
#pragma unroll
      for (int ni = 0; ni < 4; ++ni)
        acc[mi][ni] = __builtin_amdgcn_mfma_f32_16x16x32_bf16(bfr[ni], af[mi], acc[mi][ni], 0, 0, 0);
    __builtin_amdgcn_s_setprio(0);
    __builtin_amdgcn_sched_barrier(0);
    __builtin_amdgcn_s_barrier();
    if (kt + 3 < nk) STAGE(kt + 3, bb);
    bb = (bb == 2) ? 0 : bb + 1;
  }

  const float* bias = b0;
  unsigned short* outb = o0;
  int nbase = n0, ostride = N;
  if (split) {                          // 256-tile lies in exactly one 512-col segment
    int seg = n0 >> 9;
    if (seg == 1) { bias = b1; outb = o1; }
    else if (seg == 2) { bias = b2; outb = o2; }
    nbase = n0 & 511; ostride = 512;
  }
#pragma unroll
  for (int ni = 0; ni < 4; ++ni) {
    int colb = nbase + wid * 64 + ni * 16 + hi * 4;
    float4 bv = *(const float4*)(bias + colb);
#pragma unroll
    for (int mi = 0; mi < 8; ++mi) {
      int row = m0 + mi * 16 + c16;
      float v0 = acc[mi][ni][0] + bv.x;
      float v1 = acc[mi][ni][1] + bv.y;
      float v2 = acc[mi][ni][2] + bv.z;
      float v3 = acc[mi][ni][3] + bv.w;
      if (relu) { v0 = fmaxf(v0, 0.f); v1 = fmaxf(v1, 0.f); v2 = fmaxf(v2, 0.f); v3 = fmaxf(v3, 0.f); }
      *(uint2*)(outb + (size_t)row * ostride + colb) = make_uint2(pkbf(v0, v1), pkbf(v2, v3));
    }
  }
}

// ------------- bf16 MFMA GEMM, 128x128 tile, BK=32, 4 waves (each 64x64) -------------
// for N=512 shapes: grid = 4*128 = 512 wgs -> full chip at 2 wg/CU, direct bf16 out
__global__ __launch_bounds__(256, 2) void gemm128_kernel(
    const unsigned short* __restrict__ A, const unsigned short* __restrict__ Bt,
    const float* __restrict__ bias, unsigned short* __restrict__ outb,
    int K, int N, int nbx) {
  __shared__ unsigned short As[3][128 * 32];   // 8 KB each
  __shared__ unsigned short Bs[3][128 * 32];   // 8 KB each -> 48 KB total
  int nwg = nbx * (M_ / 128);
  int cpx = nwg >> 3;
  int id = blockIdx.x;
  int wg = (id & 7) * cpx + (id >> 3);         // bijective: nwg % 8 == 0
  int bx = wg % nbx, by = wg / nbx;
  int m0 = by * 128, n0 = bx * 128;

  int tid = threadIdx.x, lane = tid & 63, wid = tid >> 6;
  int wm = wid >> 1, wn = wid & 1;
  f32x4 acc[4][4];
#pragma unroll
  for (int mi = 0; mi < 4; ++mi)
#pragma unroll
    for (int ni = 0; ni < 4; ++ni) acc[mi][ni] = (f32x4)0.0f;

  int srow = lane >> 2, scol = (lane & 3) * 8;
  const unsigned short* Abase = A + (size_t)m0 * K;
  const unsigned short* Bbase = Bt + (size_t)n0 * K;
  int c16 = lane & 15, hi = lane >> 4;
  int koff = hi * 8;
  int arow = wm * 64 + c16, brow = wn * 64 + c16;
  int nk = K >> 5;

  auto STAGE = [&](int kt, int bb) {
    int k0 = kt * 32;
#pragma unroll
    for (int i = 0; i < 2; ++i) {
      int c = wid * 2 + i;
      gload_lds16(Abase + (size_t)(c * 16 + srow) * K + k0 + scol, (char*)As[bb] + c * 1024);
      gload_lds16(Bbase + (size_t)(c * 16 + srow) * K + k0 + scol, (char*)Bs[bb] + c * 1024);
    }
  };

  STAGE(0, 0); STAGE(1, 1); STAGE(2, 2);
  int bb = 0;
  for (int kt = 0; kt < nk; ++kt) {
    int rem = nk - 1 - kt;
    if (rem >= 2)      asm volatile("s_waitcnt vmcnt(8)" ::: "memory");
    else if (rem == 1) asm volatile("s_waitcnt vmcnt(4)" ::: "memory");
    else               asm volatile("s_waitcnt vmcnt(0)" ::: "memory");
    __builtin_amdgcn_s_barrier();
    __builtin_amdgcn_sched_barrier(0);
    bf16x8 af[4], bfr[4];
#pragma unroll
    for (int mi = 0; mi < 4; ++mi) af[mi] = *(const bf16x8*)&As[bb][(arow + mi * 16) * 32 + koff];
#pragma unroll
    for (int ni = 0; ni < 4; ++ni) bfr[ni] = *(const bf16x8*)&Bs[bb][(brow + ni * 16) * 32 + koff];
    __builtin_amdgcn_s_setprio(1);
#pragma unroll
    for (int mi = 0; mi < 4; ++mi)
#pragma unroll
      for (int ni = 0; ni < 4; ++ni)
        acc[mi][ni] = __builtin_amdgcn_mfma_f32_16x16x32_bf16(bfr[ni], af[mi], acc[mi][ni], 0, 0, 0);
    __builtin_amdgcn_s_setprio(0);
    __builtin_amdgcn_sched_barrier(0);
    __builtin_amdgcn_s_barrier();
    if (kt + 3 < nk) STAGE(kt + 3, bb);
    bb = (bb == 2) ? 0 : bb + 1;
  }

#pragma unroll
  for (int ni = 0; ni < 4; ++ni) {
    int colb = n0 + wn * 64 + ni * 16 + hi * 4;
    float4 bv = *(const float4*)(bias + colb);
#pragma unroll
    for (int mi = 0; mi < 4; ++mi) {
      int row = m0 + wm * 64 + mi * 16 + c16;
      float v0 = acc[mi][ni][0] + bv.x;
      float v1 = acc[mi][ni][1] + bv.y;
      float v2 = acc[mi][ni][2] + bv.z;
      float v3 = acc[mi][ni][3] + bv.w;
      *(uint2*)(outb + (size_t)row * N + colb) = make_uint2(pkbf(v0, v1), pkbf(v2, v3));
    }
  }
}

// ------------- fused add-residual + LayerNorm (bf16 in, bf16 out), one row per block -------------
__global__ __launch_bounds__(128) void addln_kernel(
    const unsigned short* __restrict__ Y, const unsigned short* __restrict__ R,
    const float* __restrict__ g, const float* __restrict__ b,
    unsigned short* __restrict__ Out) {
  __shared__ float red[2], red2[2];
  int row = blockIdx.x, t = threadIdx.x;
  size_t o = (size_t)row * 512 + t * 4;
  ushort4 yv = *(const ushort4*)(Y + o);
  ushort4 rv = *(const ushort4*)(R + o);
  float v0 = bf2f(yv.x) + bf2f(rv.x);
  float v1 = bf2f(yv.y) + bf2f(rv.y);
  float v2 = bf2f(yv.z) + bf2f(rv.z);
  float v3 = bf2f(yv.w) + bf2f(rv.w);
  float s = v0 + v1 + v2 + v3;
#pragma unroll
  for (int m = 1; m < 64; m <<= 1) s += __shfl_xor(s, m);
  if ((t & 63) == 0) red[t >> 6] = s;
  __syncthreads();
  float mean = (red[0] + red[1]) * (1.0f / 512.0f);
  float d0 = v0 - mean, d1 = v1 - mean, d2 = v2 - mean, d3 = v3 - mean;
  float sq = d0 * d0 + d1 * d1 + d2 * d2 + d3 * d3;
#pragma unroll
  for (int m = 1; m < 64; m <<= 1) sq += __shfl_xor(sq, m);
  if ((t & 63) == 0) red2[t >> 6] = sq;
  __syncthreads();
  float var = (red2[0] + red2[1]) * (1.0f / 512.0f);
  float rstd = rsqrtf(var + 1e-5f);
  float4 gg = *(const float4*)(g + t * 4);
  float4 bb = *(const float4*)(b + t * 4);
  float y0 = d0 * rstd * gg.x + bb.x;
  float y1 = d1 * rstd * gg.y + bb.y;
  float y2 = d2 * rstd * gg.z + bb.z;
  float y3 = d3 * rstd * gg.w + bb.w;
  *(uint2*)(Out + o) = make_uint2(pkbf(y0, y1), pkbf(y2, y3));
}

// ------------- flash attention, 32x32 swapped-QK^T, in-register softmax -------------
// grid (2, 256): wave owns 64 q rows (two 32-row sub-blocks)
__global__ __launch_bounds__(256) void attn_kernel(
    const unsigned short* __restrict__ Q, const unsigned short* __restrict__ Kb,
    const unsigned short* __restrict__ Vb, unsigned short* __restrict__ Ctx) {
  __shared__ char KlB[8192];   // K tile [64 k][64 d] bf16, XOR-swizzled rows
  __shared__ char VtB[8192];   // V^T tile [64 d][64 k] bf16, XOR-swizzled rows
  int g = blockIdx.y;
  int q0 = blockIdx.x * 256;
  const unsigned short* Kg = Kb + (size_t)g * 512 * 64;
  const unsigned short* Vg = Vb + (size_t)g * 512 * 64;
  int tid = threadIdx.x, lane = tid & 63, wid = tid >> 6;
  int l31 = lane & 31, h = lane >> 5;
  bool lo = (lane < 32);
  int qrowA = q0 + wid * 64 + l31;
  int qrowB = qrowA + 32;
  const float sc2 = 0.125f * 1.44269504f;

  bf16x8 qfa[4], qfb[4];
  {
    const unsigned short* qpa = Q + ((size_t)g * 512 + qrowA) * 64;
    const unsigned short* qpb = Q + ((size_t)g * 512 + qrowB) * 64;
#pragma unroll
    for (int c = 0; c < 4; ++c) {
      bf16x8 ra = *(const bf16x8*)(qpa + c * 16 + h * 8);
      bf16x8 rb = *(const bf16x8*)(qpb + c * 16 + h * 8);
      union { unsigned int u[4]; bf16x8 v; } ua, ub;
#pragma unroll
      for (int j = 0; j < 4; ++j) {
        ua.u[j] = pkbf(bf2f((unsigned short)ra[2 * j]) * sc2,
                       bf2f((unsigned short)ra[2 * j + 1]) * sc2);
        ub.u[j] = pkbf(bf2f((unsigned short)rb[2 * j]) * sc2,
                       bf2f((unsigned short)rb[2 * j + 1]) * sc2);
      }
      qfa[c] = ua.v; qfb[c] = ub.v;
    }
  }

  f32x16 cA0 = (f32x16)0.0f, cA1 = (f32x16)0.0f;   // O^T halves, sub-block A
  f32x16 cB0 = (f32x16)0.0f, cB1 = (f32x16)0.0f;   // sub-block B
  float mrA = -3.0e38f, lsA = 0.0f;
  float mrB = -3.0e38f, lsB = 0.0f;

  for (int kt = 0; kt < 8; ++kt) {
    __syncthreads();
    {
      int row = tid >> 2;
      size_t base = (size_t)(kt * 64 + row) * 64;
#pragma unroll
      for (int i = 0; i < 2; ++i) {
        int cb = ((tid & 3) + 4 * i) * 16;       // byte col within 128B row
        bf16x8 kv = *(const bf16x8*)(Kg + base + cb / 2);
        *(bf16x8*)(KlB + row * 128 + (cb ^ ((row & 7) << 4))) = kv;
        bf16x8 vv = *(const bf16x8*)(Vg + base + cb / 2);
#pragma unroll
        for (int j = 0; j < 8; ++j) {
          int d = cb / 2 + j;
          *(unsigned short*)(VtB + d * 128 + ((2 * row) ^ ((d & 7) << 4))) =
              (unsigned short)vv[j];
        }
      }
    }
    __syncthreads();

#pragma unroll
    for (int sub = 0; sub < 2; ++sub) {
      f32x16 s0 = (f32x16)0.0f, s1 = (f32x16)0.0f;
#pragma unroll
      for (int c = 0; c < 4; ++c) {
        int cb = 32 * c + 16 * h;
        int sw = cb ^ ((l31 & 7) << 4);
        bf16x8 k0 = *(const bf16x8*)(KlB + l31 * 128 + sw);
        bf16x8 k1 = *(const bf16x8*)(KlB + (32 + l31) * 128 + sw);
        bf16x8 qf = sub ? qfb[c] : qfa[c];
        s0 = __builtin_amdgcn_mfma_f32_32x32x16_bf16(k0, qf, s0, 0, 0, 0);
        s1 = __builtin_amdgcn_mfma_f32_32x32x16_bf16(k1, qf, s1, 0, 0, 0);
      }

      float mr = sub ? mrB : mrA;
      float ls = sub ? lsB : lsA;
      float pm = s0[0];
#pragma unroll
      for (int i = 1; i < 16; ++i) pm = fmaxf(pm, s0[i]);
#pragma unroll
      for (int i = 0; i < 16; ++i) pm = fmaxf(pm, s1[i]);
      pm = fmaxf(pm, __shfl_xor(pm, 32));
      // T13 defer-max: skip O-rescale while tile max stays within 2^8 of running max
      if (!__all(pm <= mr + 8.0f)) {
        float mnew = fmaxf(mr, pm);
        float alpha = exp2f(mr - mnew);
        ls *= alpha;
        if (sub) {
#pragma unroll
          for (int i = 0; i < 16; ++i) { cB0[i] *= alpha; cB1[i] *= alpha; }
        } else {
#pragma unroll
          for (int i = 0; i < 16; ++i) { cA0[i] *= alpha; cA1[i] *= alpha; }
        }
        mr = mnew;
      }
      float p[32];
      float rs = 0.0f;
#pragma unroll
      for (int i = 0; i < 16; ++i) { p[i] = exp2f(s0[i] - mr); rs += p[i]; }
#pragma unroll
      for (int i = 0; i < 16; ++i) { p[16 + i] = exp2f(s1[i] - mr); rs += p[16 + i]; }
      float rso = __shfl_xor(rs, 32);
      ls += rs + rso;
      if (sub) { mrB = mr; lsB = ls; } else { mrA = mr; lsA = ls; }

      union { unsigned int u[4]; bf16x8 v; } pa[4];
#pragma unroll
      for (int t = 0; t < 2; ++t) {
#pragma unroll
        for (int u = 0; u < 2; ++u) {
#pragma unroll
          for (int pr = 0; pr < 2; ++pr) {
            const int b0i = t * 16 + 8 * u;
            unsigned int a  = prm(p[b0i + 2 * pr],     p[b0i + 2 * pr + 1]);
            unsigned int b  = prm(p[b0i + 4 + 2 * pr], p[b0i + 4 + 2 * pr + 1]);
            unsigned int sa = __shfl_xor(a, 32);
            unsigned int sb = __shfl_xor(b, 32);
            pa[t * 2 + u].u[pr]     = lo ? a  : sb;
            pa[t * 2 + u].u[2 + pr] = lo ? sa : b;
          }
        }
      }

#pragma unroll
      for (int kc = 0; kc < 4; ++kc) {
        int cb = 32 * kc + 16 * h;
        int sw = cb ^ ((l31 & 7) << 4);
        bf16x8 v0 = *(const bf16x8*)(VtB + l31 * 128 + sw);
        bf16x8 v1 = *(const bf16x8*)(VtB + (32 + l31) * 128 + sw);
        if (sub) {
          cB0 = __builtin_amdgcn_mfma_f32_32x32x16_bf16(v0, pa[kc].v, cB0, 0, 0, 0);
          cB1 = __builtin_amdgcn_mfma_f32_32x32x16_bf16(v1, pa[kc].v, cB1, 0, 0, 0);
        } else {
          cA0 = __builtin_amdgcn_mfma_f32_32x32x16_bf16(v0, pa[kc].v, cA0, 0, 0, 0);
          cA1 = __builtin_amdgcn_mfma_f32_32x32x16_bf16(v1, pa[kc].v, cA1, 0, 0, 0);
        }
      }
    }
  }

#pragma unroll
  for (int sub = 0; sub < 2; ++sub) {
    float inv = 1.0f / (sub ? lsB : lsA);
    int qrow = sub ? qrowB : qrowA;
    unsigned short* cp = Ctx + ((size_t)g * 512 + qrow) * 64;
#pragma unroll
    for (int dh = 0; dh < 2; ++dh) {
#pragma unroll
      for (int rq = 0; rq < 4; ++rq) {
        float e0 = (sub ? (dh ? cB1[rq * 4 + 0] : cB0[rq * 4 + 0]) : (dh ? cA1[rq * 4 + 0] : cA0[rq * 4 + 0])) * inv;
        float e1 = (sub ? (dh ? cB1[rq * 4 + 1] : cB0[rq * 4 + 1]) : (dh ? cA1[rq * 4 + 1] : cA0[rq * 4 + 1])) * inv;
        float e2 = (sub ? (dh ? cB1[rq * 4 + 2] : cB0[rq * 4 + 2]) : (dh ? cA1[rq * 4 + 2] : cA0[rq * 4 + 2])) * inv;
        float e3 = (sub ? (dh ? cB1[rq * 4 + 3] : cB0[rq * 4 + 3]) : (dh ? cA1[rq * 4 + 3] : cA0[rq * 4 + 3])) * inv;
        int d0 = dh * 32 + rq * 8 + h * 4;
        *(uint2*)(cp + d0) = make_uint2(pkbf(e0, e1), pkbf(e2, e3));
      }
    }
  }
}

// ------------- final FC: out[32][1000] = act[32][262144](bf16) @ Wfc + bfc (split-K) -------------
// 512 threads, thread t owns cols {t, t+512}; 4 k per inner iter; FMA/HBM-bound
#define KCH 1024
__global__ __launch_bounds__(512) void fc_part_kernel(const unsigned short* __restrict__ act,
                                                      const float* __restrict__ Wfc,
                                                      float* __restrict__ part) {
  __shared__ float al[32][256];
  int t = threadIdx.x;
  int kc = blockIdx.x;
  size_t k0 = (size_t)kc * KCH;
  int o1 = t;               // < 1000 always
  int o2 = 512 + t;
  bool a2 = (o2 < O_);
  float acc1[32], acc2[32];
#pragma unroll
  for (int bb = 0; bb < 32; ++bb) { acc1[bb] = 0.0f; acc2[bb] = 0.0f; }
  for (int sub = 0; sub < KCH / 256; ++sub) {
    __syncthreads();
    for (int i = t; i < 32 * 128; i += 512) {
      int bb = i >> 7, kk = (i & 127) * 2;
      ushort2 u = *(const ushort2*)(act + (size_t)bb * 262144 + k0 + sub * 256 + kk);
      al[bb][kk] = bf2f(u.x);
      al[bb][kk + 1] = bf2f(u.y);
    }
    __syncthreads();
    const float* wp = Wfc + (k0 + sub * 256) * O_;
    for (int kk = 0; kk < 256; kk += 4) {
      const float* wr = wp + (size_t)kk * O_;
      float w10 = wr[o1];
      float w11 = wr[O_ + o1];
      float w12 = wr[2 * O_ + o1];
      float w13 = wr[3 * O_ + o1];
      float w20 = a2 ? wr[o2] : 0.0f;
      float w21 = a2 ? wr[O_ + o2] : 0.0f;
      float w22 = a2 ? wr[2 * O_ + o2] : 0.0f;
      float w23 = a2 ? wr[3 * O_ + o2] : 0.0f;
#pragma unroll
      for (int bb = 0; bb < 32; ++bb) {
        f32x4 av = *(const f32x4*)&al[bb][kk];
        acc1[bb] = fmaf(av[0], w10, acc1[bb]);
        acc1[bb] = fmaf(av[1], w11, acc1[bb]);
        acc1[bb] = fmaf(av[2], w12, acc1[bb]);
        acc1[bb] = fmaf(av[3], w13, acc1[bb]);
        acc2[bb] = fmaf(av[0], w20, acc2[bb]);
        acc2[bb] = fmaf(av[1], w21, acc2[bb]);
        acc2[bb] = fmaf(av[2], w22, acc2[bb]);
        acc2[bb] = fmaf(av[3], w23, acc2[bb]);
      }
    }
  }
#pragma unroll
  for (int bb = 0; bb < 32; ++bb) {
    part[((size_t)kc * 32 + bb) * O_ + o1] = acc1[bb];
    if (a2) part[((size_t)kc * 32 + bb) * O_ + o2] = acc2[bb];
  }
}

__global__ void fc_reduce_kernel(const float* __restrict__ part, const float* __restrict__ bfc,
                                 float* __restrict__ out) {
  int o = blockIdx.x * 256 + threadIdx.x;
  int b = blockIdx.y;
  if (o >= O_) return;
  float s = bfc[o];
  for (int c = 0; c < 256; ++c) s += part[((size_t)c * 32 + b) * O_ + o];
  out[(size_t)b * O_ + o] = s;
}

extern "C" void kernel_launch(void* const* d_in, const int* in_sizes, int n_in,
                              void* d_out, int out_size, void* d_ws, size_t ws_size,
                              hipStream_t stream) {
  const int*   x   = (const int*)d_in[0];
  const float* emb = (const float*)d_in[2];
  const float* Wq  = (const float*)d_in[3];
  const float* bq  = (const float*)d_in[4];
  const float* Wk  = (const float*)d_in[5];
  const float* bk  = (const float*)d_in[6];
  const float* Wv  = (const float*)d_in[7];
  const float* bv  = (const float*)d_in[8];
  const float* Wo  = (const float*)d_in[9];
  const float* bo  = (const float*)d_in[10];
  const float* g1  = (const float*)d_in[11];
  const float* bn1 = (const float*)d_in[12];
  const float* W1  = (const float*)d_in[13];
  const float* bf1 = (const float*)d_in[14];
  const float* W2  = (const float*)d_in[15];
  const float* bf2 = (const float*)d_in[16];
  const float* g2  = (const float*)d_in[17];
  const float* bn2 = (const float*)d_in[18];
  const float* Wfc = (const float*)d_in[19];
  const float* bfc = (const float*)d_in[20];
  float* out = (float*)d_out;

  char* ws = (char*)d_ws;
  size_t off = 0;
  auto take = [&](size_t bytes) { char* p = ws + off; off += (bytes + 255) & ~(size_t)255; return p; };
  float*          pe   = (float*)take((size_t)512 * 512 * 4);
  unsigned short* wqkv = (unsigned short*)take((size_t)L_ * 1536 * 512 * 2);
  unsigned short* wot  = (unsigned short*)take((size_t)L_ * 512 * 512 * 2);
  unsigned short* w1t  = (unsigned short*)take((size_t)L_ * 2048 * 512 * 2);
  unsigned short* w2t  = (unsigned short*)take((size_t)L_ * 512 * 2048 * 2);
  unsigned short* xb   = (unsigned short*)take((size_t)M_ * 512 * 2);
  unsigned short* qb   = (unsigned short*)take((size_t)M_ * 512 * 2);
  unsigned short* kb   = (unsigned short*)take((size_t)M_ * 512 * 2);
  unsigned short* vb   = (unsigned short*)take((size_t)M_ * 512 * 2);
  unsigned short* cxb  = (unsigned short*)take((size_t)M_ * 512 * 2);
  unsigned short* hb   = (unsigned short*)take((size_t)M_ * 512 * 2);
  unsigned short* t1   = (unsigned short*)take((size_t)M_ * 512 * 2);
  unsigned short* f1b  = qb;          // alias: q/k/v/cxb region (67 MB contiguous) free during FFN
  float*          part = (float*)qb;  // alias: free after last layer (needs 32.8 MB)

  pe_kernel<<<1024, 256, 0, stream>>>(pe);
  wconv_kernel<<<dim3(16, 16, L_), 256, 0, stream>>>(Wq, wqkv,          512, 512,  (size_t)1536 * 512);
  wconv_kernel<<<dim3(16, 16, L_), 256, 0, stream>>>(Wk, wqkv + 262144, 512, 512,  (size_t)1536 * 512);
  wconv_kernel<<<dim3(16, 16, L_), 256, 0, stream>>>(Wv, wqkv + 524288, 512, 512,  (size_t)1536 * 512);
  wconv_kernel<<<dim3(16, 16, L_), 256, 0, stream>>>(Wo, wot,           512, 512,  (size_t)512 * 512);
  wconv_kernel<<<dim3(16, 64, L_), 256, 0, stream>>>(W1, w1t,           512, 2048, (size_t)2048 * 512);
  wconv_kernel<<<dim3(64, 16, L_), 256, 0, stream>>>(W2, w2t,           2048, 512, (size_t)512 * 2048);
  embed_kernel<<<M_, 128, 0, stream>>>(x, emb, pe, xb);

  for (int l = 0; l < L_; ++l) {
    // QKV: N=1536 -> nbx=6, grid 768 (128x256 tile)
    gemm_kernel<<<768, 256, 0, stream>>>(
        xb, wqkv + (size_t)l * 1536 * 512,
        bq + l * 512, bk + l * 512, bv + l * 512,
        qb, kb, vb, 512, 1536, 0, 1, 6);
    attn_kernel<<<dim3(2, G_), 256, 0, stream>>>(qb, kb, vb, cxb);
    // O-proj: N=512 -> 128x128 tile, nbx=4, grid 512 = full chip
    gemm128_kernel<<<512, 256, 0, stream>>>(
        cxb, wot + (size_t)l * 512 * 512, bo + l * 512, t1, 512, 512, 4);
    addln_kernel<<<M_, 128, 0, stream>>>(t1, xb, g1 + l * 512, bn1 + l * 512, hb);
    // FF1: N=2048 -> nbx=8, grid 1024 (128x256 tile)
    gemm_kernel<<<1024, 256, 0, stream>>>(
        hb, w1t + (size_t)l * 2048 * 512,
        bf1 + l * 2048, nullptr, nullptr,
        f1b, nullptr, nullptr, 512, 2048, 1, 0, 8);
    // FF2: N=512, K=2048 -> 128x128 tile, nbx=4, grid 512 = full chip
    gemm128_kernel<<<512, 256, 0, stream>>>(
        f1b, w2t + (size_t)l * 512 * 2048, bf2 + l * 512, t1, 2048, 512, 4);
    addln_kernel<<<M_, 128, 0, stream>>>(t1, hb, g2 + l * 512, bn2 + l * 512, xb);
  }

  fc_part_kernel<<<256, 512, 0, stream>>>(xb, Wfc, part);
  fc_reduce_kernel<<<dim3(4, 32), 256, 0, stream>>>(part, bfc, out);
}

// Round 11
// 1872.155 us; speedup vs baseline: 1.0725x; 1.0230x over previous
//
#include <hip/hip_runtime.h>
#include <cstdint>
#include <cstddef>

#define S_  512
#define B_  32
#define D_  512
#define FF_ 2048
#define L_  6
#define O_  1000
#define M_  (B_*S_)     // 16384 rows of activations
#define G_  256         // attention groups (buggy reshape semantics)
#define DH_ 64

typedef __attribute__((ext_vector_type(8))) short bf16x8;
typedef __attribute__((ext_vector_type(4))) float f32x4;
typedef __attribute__((ext_vector_type(16))) float f32x16;

__device__ __forceinline__ unsigned short f2bf(float f) {
  unsigned int u = __builtin_bit_cast(unsigned int, f);
  u = (u + 0x7fffu + ((u >> 16) & 1u)) >> 16;
  return (unsigned short)u;
}
__device__ __forceinline__ float bf2f(unsigned short u) {
  return __builtin_bit_cast(float, (unsigned int)u << 16);
}
__device__ __forceinline__ unsigned int pkbf(float a, float b) {
  return (unsigned int)f2bf(a) | ((unsigned int)f2bf(b) << 16);
}
// truncating pack of 2 floats -> 2 bf16 in one v_perm_b32 (hi16 of each)
__device__ __forceinline__ unsigned int prm(float a, float b) {
  return __builtin_amdgcn_perm(__builtin_bit_cast(unsigned int, b),
                               __builtin_bit_cast(unsigned int, a), 0x07060302u);
}
__device__ __forceinline__ void gload_lds16(const void* g, void* l) {
  __builtin_amdgcn_global_load_lds(
      (const __attribute__((address_space(1))) unsigned int*)g,
      (__attribute__((address_space(3))) unsigned int*)l, 16, 0, 0);
}

// ---------------- positional encoding table [512][512] f32 ----------------
__global__ void pe_kernel(float* __restrict__ pe) {
  int i = blockIdx.x * 256 + threadIdx.x;
  int s = i >> 9, d = i & 511;
  double de = (double)(d & ~1);
  double ang = (double)s * exp(de * (-9.210340371976184 / 512.0));
  pe[i] = (d & 1) ? (float)cos(ang) : (float)sin(ang);
}

// ------------- transpose-convert W [z][K][N] f32 -> Wt [z-stride ozs][N][K] bf16 -------------
__global__ void wconv_kernel(const float* __restrict__ W, unsigned short* __restrict__ Wt,
                             int K, int N, size_t ozs) {
  __shared__ float tile[32][33];
  const float* Wl = W + (size_t)blockIdx.z * K * N;
  unsigned short* Wtl = Wt + (size_t)blockIdx.z * ozs;
  int k0 = blockIdx.x * 32, n0 = blockIdx.y * 32;
  int c = threadIdx.x & 31, rb = threadIdx.x >> 5;
#pragma unroll
  for (int i = 0; i < 4; ++i) {
    int r = rb + i * 8;
    tile[r][c] = Wl[(size_t)(k0 + r) * N + n0 + c];
  }
  __syncthreads();
#pragma unroll
  for (int i = 0; i < 4; ++i) {
    int r = rb + i * 8;
    Wtl[(size_t)(n0 + r) * K + k0 + c] = f2bf(tile[c][r]);
  }
}

// ------------- embedding + PE (bf16 out only) -------------
__global__ void embed_kernel(const int* __restrict__ x, const float* __restrict__ emb,
                             const float* __restrict__ pe, unsigned short* __restrict__ xb) {
  int bi = blockIdx.x;            // s*B + b
  int s = bi / B_, b = bi % B_;
  int tok = x[s * B_ + b];
  int d = threadIdx.x * 4;
  float4 e = *(const float4*)(emb + (size_t)tok * D_ + d);
  float4 p = *(const float4*)(pe + (size_t)s * D_ + d);
  size_t o = ((size_t)b * S_ + s) * D_ + d;
  ushort4 u;
  u.x = f2bf(e.x + p.x); u.y = f2bf(e.y + p.y);
  u.z = f2bf(e.z + p.z); u.w = f2bf(e.w + p.w);
  *(ushort4*)(xb + o) = u;
}

// ------------- bf16 MFMA GEMM, 128(M)x256(N) tile, BK=32, 4 waves (each 128Mx64N) -------------
// triple-buffered counted-vmcnt pipeline; used for FF1 (N=2048)
__global__ __launch_bounds__(256, 2) void gemm_kernel(
    const unsigned short* __restrict__ A, const unsigned short* __restrict__ Bt,
    const float* __restrict__ bias, unsigned short* __restrict__ outb,
    int K, int N, int relu, int nbx) {
  __shared__ unsigned short As[3][128 * 32];   // 8 KB each
  __shared__ unsigned short Bs[3][256 * 32];   // 16 KB each -> 72 KB total, 2 wg/CU
  int nwg = nbx * (M_ / 128);
  int cpx = nwg >> 3;
  int id = blockIdx.x;
  int wg = (id & 7) * cpx + (id >> 3);         // bijective: nwg % 8 == 0
  int bx = wg % nbx, by = wg / nbx;
  int m0 = by * 128, n0 = bx * 256;

  int tid = threadIdx.x, lane = tid & 63, wid = tid >> 6;   // wid 0..3
  f32x4 acc[8][4];
#pragma unroll
  for (int mi = 0; mi < 8; ++mi)
#pragma unroll
    for (int ni = 0; ni < 4; ++ni) acc[mi][ni] = (f32x4)0.0f;

  int srow = lane >> 2, scol = (lane & 3) * 8;
  const unsigned short* Abase = A + (size_t)m0 * K;
  const unsigned short* Bbase = Bt + (size_t)n0 * K;
  int c16 = lane & 15, hi = lane >> 4;
  int koff = hi * 8;
  int brow = wid * 64 + c16;
  int nk = K >> 5;

  auto STAGE = [&](int kt, int bb) {
    int k0 = kt * 32;
#pragma unroll
    for (int i = 0; i < 6; ++i) {
      int c = wid * 6 + i;
      if (c < 8) {
        gload_lds16(Abase + (size_t)(c * 16 + srow) * K + k0 + scol, (char*)As[bb] + c * 1024);
      } else {
        int c2 = c - 8;
        gload_lds16(Bbase + (size_t)(c2 * 16 + srow) * K + k0 + scol, (char*)Bs[bb] + c2 * 1024);
      }
    }
  };

  STAGE(0, 0); STAGE(1, 1); STAGE(2, 2);
  int bb = 0;
  for (int kt = 0; kt < nk; ++kt) {
    int rem = nk - 1 - kt;
    if (rem >= 2)      asm volatile("s_waitcnt vmcnt(12)" ::: "memory");
    else if (rem == 1) asm volatile("s_waitcnt vmcnt(6)" ::: "memory");
    else               asm volatile("s_waitcnt vmcnt(0)" ::: "memory");
    __builtin_amdgcn_s_barrier();
    __builtin_amdgcn_sched_barrier(0);
    bf16x8 af[8], bfr[4];
#pragma unroll
    for (int mi = 0; mi < 8; ++mi) af[mi] = *(const bf16x8*)&As[bb][(mi * 16 + c16) * 32 + koff];
#pragma unroll
    for (int ni = 0; ni < 4; ++ni) bfr[ni] = *(const bf16x8*)&Bs[bb][(brow + ni * 16) * 32 + koff];
    __builtin_amdgcn_s_setprio(1);
#pragma unroll
    for (int mi = 0; mi < 8; ++mi)
#pragma unroll
      for (int ni = 0; ni < 4; ++ni)
        acc[mi][ni] = __builtin_amdgcn_mfma_f32_16x16x32_bf16(bfr[ni], af[mi], acc[mi][ni], 0, 0, 0);
    __builtin_amdgcn_s_setprio(0);
    __builtin_amdgcn_sched_barrier(0);
    __builtin_amdgcn_s_barrier();
    if (kt + 3 < nk) STAGE(kt + 3, bb);
    bb = (bb == 2) ? 0 : bb + 1;
  }

#pragma unroll
  for (int ni = 0; ni < 4; ++ni) {
    int colb = n0 + wid * 64 + ni * 16 + hi * 4;
    float4 bv = *(const float4*)(bias + colb);
#pragma unroll
    for (int mi = 0; mi < 8; ++mi) {
      int row = m0 + mi * 16 + c16;
      float v0 = acc[mi][ni][0] + bv.x;
      float v1 = acc[mi][ni][1] + bv.y;
      float v2 = acc[mi][ni][2] + bv.z;
      float v3 = acc[mi][ni][3] + bv.w;
      if (relu) { v0 = fmaxf(v0, 0.f); v1 = fmaxf(v1, 0.f); v2 = fmaxf(v2, 0.f); v3 = fmaxf(v3, 0.f); }
      *(uint2*)(outb + (size_t)row * N + colb) = make_uint2(pkbf(v0, v1), pkbf(v2, v3));
    }
  }
}

// ------------- bf16 MFMA GEMM, 128x128 tile, BK=32, double-buffered, 3 wg/CU -------------
// acc = 64 VGPR -> 3 waves/SIMD fit; 12 waves/CU hide the barrier drain via TLP.
// split=1: N logical 1536, 128-col tile lies in one 512-col segment -> {o0,o1,o2}
__global__ __launch_bounds__(256, 3) void gemm128_kernel(
    const unsigned short* __restrict__ A, const unsigned short* __restrict__ Bt,
    const float* __restrict__ b0, const float* __restrict__ b1, const float* __restrict__ b2,
    unsigned short* __restrict__ o0, unsigned short* __restrict__ o1, unsigned short* __restrict__ o2,
    int K, int N, int relu, int split, int nbx) {
  __shared__ unsigned short As[2][128 * 32];   // 8 KB each
  __shared__ unsigned short Bs[2][128 * 32];   // 8 KB each -> 32 KB total
  int nwg = nbx * (M_ / 128);
  int cpx = nwg >> 3;
  int id = blockIdx.x;
  int wg = (id & 7) * cpx + (id >> 3);         // bijective: nwg % 8 == 0
  int bx = wg % nbx, by = wg / nbx;
  int m0 = by * 128, n0 = bx * 128;

  int tid = threadIdx.x, lane = tid & 63, wid = tid >> 6;
  int wm = wid >> 1, wn = wid & 1;
  f32x4 acc[4][4];
#pragma unroll
  for (int mi = 0; mi < 4; ++mi)
#pragma unroll
    for (int ni = 0; ni < 4; ++ni) acc[mi][ni] = (f32x4)0.0f;

  int srow = lane >> 2, scol = (lane & 3) * 8;
  const unsigned short* Abase = A + (size_t)m0 * K;
  const unsigned short* Bbase = Bt + (size_t)n0 * K;
  int c16 = lane & 15, hi = lane >> 4;
  int koff = hi * 8;
  int arow = wm * 64 + c16, brow = wn * 64 + c16;
  int nk = K >> 5;

  auto STAGE = [&](int kt, int bb) {
    int k0 = kt * 32;
#pragma unroll
    for (int i = 0; i < 2; ++i) {
      int c = wid * 2 + i;
      gload_lds16(Abase + (size_t)(c * 16 + srow) * K + k0 + scol, (char*)As[bb] + c * 1024);
      gload_lds16(Bbase + (size_t)(c * 16 + srow) * K + k0 + scol, (char*)Bs[bb] + c * 1024);
    }
  };

  STAGE(0, 0); STAGE(1, 1);
  int bb = 0;
  for (int kt = 0; kt < nk; ++kt) {
    if (kt + 1 < nk) asm volatile("s_waitcnt vmcnt(4)" ::: "memory");
    else             asm volatile("s_waitcnt vmcnt(0)" ::: "memory");
    __builtin_amdgcn_s_barrier();       // tile kt visible
    __builtin_amdgcn_sched_barrier(0);
    bf16x8 af[4], bfr[4];
#pragma unroll
    for (int mi = 0; mi < 4; ++mi) af[mi] = *(const bf16x8*)&As[bb][(arow + mi * 16) * 32 + koff];
#pragma unroll
    for (int ni = 0; ni < 4; ++ni) bfr[ni] = *(const bf16x8*)&Bs[bb][(brow + ni * 16) * 32 + koff];
    __builtin_amdgcn_s_setprio(1);
#pragma unroll
    for (int mi = 0; mi < 4; ++mi)
#pragma unroll
      for (int ni = 0; ni < 4; ++ni)
        acc[mi][ni] = __builtin_amdgcn_mfma_f32_16x16x32_bf16(bfr[ni], af[mi], acc[mi][ni], 0, 0, 0);
    __builtin_amdgcn_s_setprio(0);
    __builtin_amdgcn_sched_barrier(0);
    __builtin_amdgcn_s_barrier();       // all waves done reading buf bb
    if (kt + 2 < nk) STAGE(kt + 2, bb);
    bb ^= 1;
  }

  const float* bias = b0;
  unsigned short* outb = o0;
  int nbase = n0, ostride = N;
  if (split) {
    int seg = n0 >> 9;
    if (seg == 1) { bias = b1; outb = o1; }
    else if (seg == 2) { bias = b2; outb = o2; }
    nbase = n0 & 511; ostride = 512;
  }
#pragma unroll
  for (int ni = 0; ni < 4; ++ni) {
    int colb = nbase + wn * 64 + ni * 16 + hi * 4;
    float4 bv = *(const float4*)(bias + colb);
#pragma unroll
    for (int mi = 0; mi < 4; ++mi) {
      int row = m0 + wm * 64 + mi * 16 + c16;
      float v0 = acc[mi][ni][0] + bv.x;
      float v1 = acc[mi][ni][1] + bv.y;
      float v2 = acc[mi][ni][2] + bv.z;
      float v3 = acc[mi][ni][3] + bv.w;
      if (relu) { v0 = fmaxf(v0, 0.f); v1 = fmaxf(v1, 0.f); v2 = fmaxf(v2, 0.f); v3 = fmaxf(v3, 0.f); }
      *(uint2*)(outb + (size_t)row * ostride + colb) = make_uint2(pkbf(v0, v1), pkbf(v2, v3));
    }
  }
}

// ------------- fused add-residual + LayerNorm (bf16 in, bf16 out), one row per block -------------
__global__ __launch_bounds__(128) void addln_kernel(
    const unsigned short* __restrict__ Y, const unsigned short* __restrict__ R,
    const float* __restrict__ g, const float* __restrict__ b,
    unsigned short* __restrict__ Out) {
  __shared__ float red[2], red2[2];
  int row = blockIdx.x, t = threadIdx.x;
  size_t o = (size_t)row * 512 + t * 4;
  ushort4 yv = *(const ushort4*)(Y + o);
  ushort4 rv = *(const ushort4*)(R + o);
  float v0 = bf2f(yv.x) + bf2f(rv.x);
  float v1 = bf2f(yv.y) + bf2f(rv.y);
  float v2 = bf2f(yv.z) + bf2f(rv.z);
  float v3 = bf2f(yv.w) + bf2f(rv.w);
  float s = v0 + v1 + v2 + v3;
#pragma unroll
  for (int m = 1; m < 64; m <<= 1) s += __shfl_xor(s, m);
  if ((t & 63) == 0) red[t >> 6] = s;
  __syncthreads();
  float mean = (red[0] + red[1]) * (1.0f / 512.0f);
  float d0 = v0 - mean, d1 = v1 - mean, d2 = v2 - mean, d3 = v3 - mean;
  float sq = d0 * d0 + d1 * d1 + d2 * d2 + d3 * d3;
#pragma unroll
  for (int m = 1; m < 64; m <<= 1) sq += __shfl_xor(sq, m);
  if ((t & 63) == 0) red2[t >> 6] = sq;
  __syncthreads();
  float var = (red2[0] + red2[1]) * (1.0f / 512.0f);
  float rstd = rsqrtf(var + 1e-5f);
  float4 gg = *(const float4*)(g + t * 4);
  float4 bb = *(const float4*)(b + t * 4);
  float y0 = d0 * rstd * gg.x + bb.x;
  float y1 = d1 * rstd * gg.y + bb.y;
  float y2 = d2 * rstd * gg.z + bb.z;
  float y3 = d3 * rstd * gg.w + bb.w;
  *(uint2*)(Out + o) = make_uint2(pkbf(y0, y1), pkbf(y2, y3));
}

// ------------- flash attention, 32x32 swapped-QK^T, in-register softmax -------------
// grid (2, 256): wave owns 64 q rows. T14 async-stage: tile t+1 global-loaded into
// registers during tile t's compute; regs written to LDS at next loop top.
__global__ __launch_bounds__(256) void attn_kernel(
    const unsigned short* __restrict__ Q, const unsigned short* __restrict__ Kb,
    const unsigned short* __restrict__ Vb, unsigned short* __restrict__ Ctx) {
  __shared__ char KlB[8192];   // K tile [64 k][64 d] bf16, XOR-swizzled rows
  __shared__ char VtB[8192];   // V^T tile [64 d][64 k] bf16, XOR-swizzled rows
  int g = blockIdx.y;
  int q0 = blockIdx.x * 256;
  const unsigned short* Kg = Kb + (size_t)g * 512 * 64;
  const unsigned short* Vg = Vb + (size_t)g * 512 * 64;
  int tid = threadIdx.x, lane = tid & 63, wid = tid >> 6;
  int l31 = lane & 31, h = lane >> 5;
  bool lo = (lane < 32);
  int qrowA = q0 + wid * 64 + l31;
  int qrowB = qrowA + 32;
  const float sc2 = 0.125f * 1.44269504f;

  bf16x8 qfa[4], qfb[4];
  {
    const unsigned short* qpa = Q + ((size_t)g * 512 + qrowA) * 64;
    const unsigned short* qpb = Q + ((size_t)g * 512 + qrowB) * 64;
#pragma unroll
    for (int c = 0; c < 4; ++c) {
      bf16x8 ra = *(const bf16x8*)(qpa + c * 16 + h * 8);
      bf16x8 rb = *(const bf16x8*)(qpb + c * 16 + h * 8);
      union { unsigned int u[4]; bf16x8 v; } ua, ub;
#pragma unroll
      for (int j = 0; j < 4; ++j) {
        ua.u[j] = pkbf(bf2f((unsigned short)ra[2 * j]) * sc2,
                       bf2f((unsigned short)ra[2 * j + 1]) * sc2);
        ub.u[j] = pkbf(bf2f((unsigned short)rb[2 * j]) * sc2,
                       bf2f((unsigned short)rb[2 * j + 1]) * sc2);
      }
      qfa[c] = ua.v; qfb[c] = ub.v;
    }
  }

  f32x16 cA0 = (f32x16)0.0f, cA1 = (f32x16)0.0f;
  f32x16 cB0 = (f32x16)0.0f, cB1 = (f32x16)0.0f;
  float mrA = -3.0e38f, lsA = 0.0f;
  float mrB = -3.0e38f, lsB = 0.0f;

  // staging geometry: thread covers row = tid>>2, two 16B chunks at byte cols cbA, cbA+64
  int rowS = tid >> 2;
  int cbA = (tid & 3) * 16;
  int cbB = cbA + 64;
  int swA = cbA ^ ((rowS & 7) << 4);
  int swB = cbB ^ ((rowS & 7) << 4);

  // prologue: tile 0 into regs
  bf16x8 kc0 = *(const bf16x8*)(Kg + (size_t)rowS * 64 + cbA / 2);
  bf16x8 kc1 = *(const bf16x8*)(Kg + (size_t)rowS * 64 + cbB / 2);
  bf16x8 vc0 = *(const bf16x8*)(Vg + (size_t)rowS * 64 + cbA / 2);
  bf16x8 vc1 = *(const bf16x8*)(Vg + (size_t)rowS * 64 + cbB / 2);

  for (int kt = 0; kt < 8; ++kt) {
    __syncthreads();   // previous tile's LDS reads complete
    // write current tile regs -> LDS (K swizzled rows; V transposed + swizzled)
    *(bf16x8*)(KlB + rowS * 128 + swA) = kc0;
    *(bf16x8*)(KlB + rowS * 128 + swB) = kc1;
#pragma unroll
    for (int j = 0; j < 8; ++j) {
      int dA = cbA / 2 + j;
      int dB = cbB / 2 + j;
      *(unsigned short*)(VtB + dA * 128 + ((2 * rowS) ^ ((dA & 7) << 4))) = (unsigned short)vc0[j];
      *(unsigned short*)(VtB + dB * 128 + ((2 * rowS) ^ ((dB & 7) << 4))) = (unsigned short)vc1[j];
    }
    // T14: issue next tile's global loads now; they land during compute below
    bf16x8 kn0, kn1, vn0, vn1;
    if (kt < 7) {
      size_t nb = (size_t)((kt + 1) * 64 + rowS) * 64;
      kn0 = *(const bf16x8*)(Kg + nb + cbA / 2);
      kn1 = *(const bf16x8*)(Kg + nb + cbB / 2);
      vn0 = *(const bf16x8*)(Vg + nb + cbA / 2);
      vn1 = *(const bf16x8*)(Vg + nb + cbB / 2);
    }
    __syncthreads();   // staged tile visible

#pragma unroll
    for (int sub = 0; sub < 2; ++sub) {
      f32x16 s0 = (f32x16)0.0f, s1 = (f32x16)0.0f;
#pragma unroll
      for (int c = 0; c < 4; ++c) {
        int cb = 32 * c + 16 * h;
        int sw = cb ^ ((l31 & 7) << 4);
        bf16x8 k0 = *(const bf16x8*)(KlB + l31 * 128 + sw);
        bf16x8 k1 = *(const bf16x8*)(KlB + (32 + l31) * 128 + sw);
        bf16x8 qf = sub ? qfb[c] : qfa[c];
        s0 = __builtin_amdgcn_mfma_f32_32x32x16_bf16(k0, qf, s0, 0, 0, 0);
        s1 = __builtin_amdgcn_mfma_f32_32x32x16_bf16(k1, qf, s1, 0, 0, 0);
      }

      float mr = sub ? mrB : mrA;
      float ls = sub ? lsB : lsA;
      float pm = s0[0];
#pragma unroll
      for (int i = 1; i < 16; ++i) pm = fmaxf(pm, s0[i]);
#pragma unroll
      for (int i = 0; i < 16; ++i) pm = fmaxf(pm, s1[i]);
      pm = fmaxf(pm, __shfl_xor(pm, 32));
      // T13 defer-max
      if (!__all(pm <= mr + 8.0f)) {
        float mnew = fmaxf(mr, pm);
        float alpha = exp2f(mr - mnew);
        ls *= alpha;
        if (sub) {
#pragma unroll
          for (int i = 0; i < 16; ++i) { cB0[i] *= alpha; cB1[i] *= alpha; }
        } else {
#pragma unroll
          for (int i = 0; i < 16; ++i) { cA0[i] *= alpha; cA1[i] *= alpha; }
        }
        mr = mnew;
      }
      float p[32];
      float rs = 0.0f;
#pragma unroll
      for (int i = 0; i < 16; ++i) { p[i] = exp2f(s0[i] - mr); rs += p[i]; }
#pragma unroll
      for (int i = 0; i < 16; ++i) { p[16 + i] = exp2f(s1[i] - mr); rs += p[16 + i]; }
      float rso = __shfl_xor(rs, 32);
      ls += rs + rso;
      if (sub) { mrB = mr; lsB = ls; } else { mrA = mr; lsA = ls; }

      union { unsigned int u[4]; bf16x8 v; } pa[4];
#pragma unroll
      for (int t = 0; t < 2; ++t) {
#pragma unroll
        for (int u = 0; u < 2; ++u) {
#pragma unroll
          for (int pr = 0; pr < 2; ++pr) {
            const int b0i = t * 16 + 8 * u;
            unsigned int a  = prm(p[b0i + 2 * pr],     p[b0i + 2 * pr + 1]);
            unsigned int b  = prm(p[b0i + 4 + 2 * pr], p[b0i + 4 + 2 * pr + 1]);
            unsigned int sa = __shfl_xor(a, 32);
            unsigned int sb = __shfl_xor(b, 32);
            pa[t * 2 + u].u[pr]     = lo ? a  : sb;
            pa[t * 2 + u].u[2 + pr] = lo ? sa : b;
          }
        }
      }

#pragma unroll
      for (int kc = 0; kc < 4; ++kc) {
        int cb = 32 * kc + 16 * h;
        int sw = cb ^ ((l31 & 7) << 4);
        bf16x8 v0 = *(const bf16x8*)(VtB + l31 * 128 + sw);
        bf16x8 v1 = *(const bf16x8*)(VtB + (32 + l31) * 128 + sw);
        if (sub) {
          cB0 = __builtin_amdgcn_mfma_f32_32x32x16_bf16(v0, pa[kc].v, cB0, 0, 0, 0);
          cB1 = __builtin_amdgcn_mfma_f32_32x32x16_bf16(v1, pa[kc].v, cB1, 0, 0, 0);
        } else {
          cA0 = __builtin_amdgcn_mfma_f32_32x32x16_bf16(v0, pa[kc].v, cA0, 0, 0, 0);
          cA1 = __builtin_amdgcn_mfma_f32_32x32x16_bf16(v1, pa[kc].v, cA1, 0, 0, 0);
        }
      }
    }

    if (kt < 7) { kc0 = kn0; kc1 = kn1; vc0 = vn0; vc1 = vn1; }
  }

#pragma unroll
  for (int sub = 0; sub < 2; ++sub) {
    float inv = 1.0f / (sub ? lsB : lsA);
    int qrow = sub ? qrowB : qrowA;
    unsigned short* cp = Ctx + ((size_t)g * 512 + qrow) * 64;
#pragma unroll
    for (int dh = 0; dh < 2; ++dh) {
#pragma unroll
      for (int rq = 0; rq < 4; ++rq) {
        float e0 = (sub ? (dh ? cB1[rq * 4 + 0] : cB0[rq * 4 + 0]) : (dh ? cA1[rq * 4 + 0] : cA0[rq * 4 + 0])) * inv;
        float e1 = (sub ? (dh ? cB1[rq * 4 + 1] : cB0[rq * 4 + 1]) : (dh ? cA1[rq * 4 + 1] : cA0[rq * 4 + 1])) * inv;
        float e2 = (sub ? (dh ? cB1[rq * 4 + 2] : cB0[rq * 4 + 2]) : (dh ? cA1[rq * 4 + 2] : cA0[rq * 4 + 2])) * inv;
        float e3 = (sub ? (dh ? cB1[rq * 4 + 3] : cB0[rq * 4 + 3]) : (dh ? cA1[rq * 4 + 3] : cA0[rq * 4 + 3])) * inv;
        int d0 = dh * 32 + rq * 8 + h * 4;
        *(uint2*)(cp + d0) = make_uint2(pkbf(e0, e1), pkbf(e2, e3));
      }
    }
  }
}

// ------------- final FC: out[32][1000] = act[32][262144](bf16) @ Wfc + bfc (split-K) -------------
#define KCH 1024
__global__ __launch_bounds__(512) void fc_part_kernel(const unsigned short* __restrict__ act,
                                                      const float* __restrict__ Wfc,
                                                      float* __restrict__ part) {
  __shared__ float al[32][256];
  int t = threadIdx.x;
  int kc = blockIdx.x;
  size_t k0 = (size_t)kc * KCH;
  int o1 = t;               // < 1000 always
  int o2 = 512 + t;
  bool a2 = (o2 < O_);
  float acc1[32], acc2[32];
#pragma unroll
  for (int bb = 0; bb < 32; ++bb) { acc1[bb] = 0.0f; acc2[bb] = 0.0f; }
  for (int sub = 0; sub < KCH / 256; ++sub) {
    __syncthreads();
    for (int i = t; i < 32 * 128; i += 512) {
      int bb = i >> 7, kk = (i & 127) * 2;
      ushort2 u = *(const ushort2*)(act + (size_t)bb * 262144 + k0 + sub * 256 + kk);
      al[bb][kk] = bf2f(u.x);
      al[bb][kk + 1] = bf2f(u.y);
    }
    __syncthreads();
    const float* wp = Wfc + (k0 + sub * 256) * O_;
    for (int kk = 0; kk < 256; kk += 4) {
      const float* wr = wp + (size_t)kk * O_;
      float w10 = wr[o1];
      float w11 = wr[O_ + o1];
      float w12 = wr[2 * O_ + o1];
      float w13 = wr[3 * O_ + o1];
      float w20 = a2 ? wr[o2] : 0.0f;
      float w21 = a2 ? wr[O_ + o2] : 0.0f;
      float w22 = a2 ? wr[2 * O_ + o2] : 0.0f;
      float w23 = a2 ? wr[3 * O_ + o2] : 0.0f;
#pragma unroll
      for (int bb = 0; bb < 32; ++bb) {
        f32x4 av = *(const f32x4*)&al[bb][kk];
        acc1[bb] = fmaf(av[0], w10, acc1[bb]);
        acc1[bb] = fmaf(av[1], w11, acc1[bb]);
        acc1[bb] = fmaf(av[2], w12, acc1[bb]);
        acc1[bb] = fmaf(av[3], w13, acc1[bb]);
        acc2[bb] = fmaf(av[0], w20, acc2[bb]);
        acc2[bb] = fmaf(av[1], w21, acc2[bb]);
        acc2[bb] = fmaf(av[2], w22, acc2[bb]);
        acc2[bb] = fmaf(av[3], w23, acc2[bb]);
      }
    }
  }
#pragma unroll
  for (int bb = 0; bb < 32; ++bb) {
    part[((size_t)kc * 32 + bb) * O_ + o1] = acc1[bb];
    if (a2) part[((size_t)kc * 32 + bb) * O_ + o2] = acc2[bb];
  }
}

__global__ void fc_reduce_kernel(const float* __restrict__ part, const float* __restrict__ bfc,
                                 float* __restrict__ out) {
  int o = blockIdx.x * 256 + threadIdx.x;
  int b = blockIdx.y;
  if (o >= O_) return;
  float s = bfc[o];
  for (int c = 0; c < 256; ++c) s += part[((size_t)c * 32 + b) * O_ + o];
  out[(size_t)b * O_ + o] = s;
}

extern "C" void kernel_launch(void* const* d_in, const int* in_sizes, int n_in,
                              void* d_out, int out_size, void* d_ws, size_t ws_size,
                              hipStream_t stream) {
  const int*   x   = (const int*)d_in[0];
  const float* emb = (const float*)d_in[2];
  const float* Wq  = (const float*)d_in[3];
  const float* bq  = (const float*)d_in[4];
  const float* Wk  = (const float*)d_in[5];
  const float* bk  = (const float*)d_in[6];
  const float* Wv  = (const float*)d_in[7];
  const float* bv  = (const float*)d_in[8];
  const float* Wo  = (const float*)d_in[9];
  const float* bo  = (const float*)d_in[10];
  const float* g1  = (const float*)d_in[11];
  const float* bn1 = (const float*)d_in[12];
  const float* W1  = (const float*)d_in[13];
  const float* bf1 = (const float*)d_in[14];
  const float* W2  = (const float*)d_in[15];
  const float* bf2 = (const float*)d_in[16];
  const float* g2  = (const float*)d_in[17];
  const float* bn2 = (const float*)d_in[18];
  const float* Wfc = (const float*)d_in[19];
  const float* bfc = (const float*)d_in[20];
  float* out = (float*)d_out;

  char* ws = (char*)d_ws;
  size_t off = 0;
  auto take = [&](size_t bytes) { char* p = ws + off; off += (bytes + 255) & ~(size_t)255; return p; };
  float*          pe   = (float*)take((size_t)512 * 512 * 4);
  unsigned short* wqkv = (unsigned short*)take((size_t)L_ * 1536 * 512 * 2);
  unsigned short* wot  = (unsigned short*)take((size_t)L_ * 512 * 512 * 2);
  unsigned short* w1t  = (unsigned short*)take((size_t)L_ * 2048 * 512 * 2);
  unsigned short* w2t  = (unsigned short*)take((size_t)L_ * 512 * 2048 * 2);
  unsigned short* xb   = (unsigned short*)take((size_t)M_ * 512 * 2);
  unsigned short* qb   = (unsigned short*)take((size_t)M_ * 512 * 2);
  unsigned short* kb   = (unsigned short*)take((size_t)M_ * 512 * 2);
  unsigned short* vb   = (unsigned short*)take((size_t)M_ * 512 * 2);
  unsigned short* cxb  = (unsigned short*)take((size_t)M_ * 512 * 2);
  unsigned short* hb   = (unsigned short*)take((size_t)M_ * 512 * 2);
  unsigned short* t1   = (unsigned short*)take((size_t)M_ * 512 * 2);
  unsigned short* f1b  = qb;          // alias: q/k/v/cxb region (67 MB contiguous) free during FFN
  float*          part = (float*)qb;  // alias: free after last layer (needs 32.8 MB)

  pe_kernel<<<1024, 256, 0, stream>>>(pe);
  wconv_kernel<<<dim3(16, 16, L_), 256, 0, stream>>>(Wq, wqkv,          512, 512,  (size_t)1536 * 512);
  wconv_kernel<<<dim3(16, 16, L_), 256, 0, stream>>>(Wk, wqkv + 262144, 512, 512,  (size_t)1536 * 512);
  wconv_kernel<<<dim3(16, 16, L_), 256, 0, stream>>>(Wv, wqkv + 524288, 512, 512,  (size_t)1536 * 512);
  wconv_kernel<<<dim3(16, 16, L_), 256, 0, stream>>>(Wo, wot,           512, 512,  (size_t)512 * 512);
  wconv_kernel<<<dim3(16, 64, L_), 256, 0, stream>>>(W1, w1t,           512, 2048, (size_t)2048 * 512);
  wconv_kernel<<<dim3(64, 16, L_), 256, 0, stream>>>(W2, w2t,           2048, 512, (size_t)512 * 2048);
  embed_kernel<<<M_, 128, 0, stream>>>(x, emb, pe, xb);

  for (int l = 0; l < L_; ++l) {
    // QKV: N=1536 -> 128x128 tile, nbx=12, grid 1536 (2 exact rounds at 3 wg/CU)
    gemm128_kernel<<<1536, 256, 0, stream>>>(
        xb, wqkv + (size_t)l * 1536 * 512,
        bq + l * 512, bk + l * 512, bv + l * 512,
        qb, kb, vb, 512, 1536, 0, 1, 12);
    attn_kernel<<<dim3(2, G_), 256, 0, stream>>>(qb, kb, vb, cxb);
    // O-proj: N=512 -> nbx=4, grid 512
    gemm128_kernel<<<512, 256, 0, stream>>>(
        cxb, wot + (size_t)l * 512 * 512,
        bo + l * 512, nullptr, nullptr,
        t1, nullptr, nullptr, 512, 512, 0, 0, 4);
    addln_kernel<<<M_, 128, 0, stream>>>(t1, xb, g1 + l * 512, bn1 + l * 512, hb);
    // FF1: N=2048 -> 128x256 tile, nbx=8, grid 1024
    gemm_kernel<<<1024, 256, 0, stream>>>(
        hb, w1t + (size_t)l * 2048 * 512, bf1 + l * 2048, f1b, 512, 2048, 1, 8);
    // FF2: N=512, K=2048 -> nbx=4, grid 512
    gemm128_kernel<<<512, 256, 0, stream>>>(
        f1b, w2t + (size_t)l * 512 * 2048,
        bf2 + l * 512, nullptr, nullptr,
        t1, nullptr, nullptr, 2048, 512, 0, 0, 4);
    addln_kernel<<<M_, 128, 0, stream>>>(t1, hb, g2 + l * 512, bn2 + l * 512, xb);
  }

  fc_part_kernel<<<256, 512, 0, stream>>>(xb, Wfc, part);
  fc_reduce_kernel<<<dim3(4, 32), 256, 0, stream>>>(part, bfc, out);
}

// Round 12
// 1856.062 us; speedup vs baseline: 1.0818x; 1.0087x over previous
//
#include <hip/hip_runtime.h>
#include <cstdint>
#include <cstddef>

#define S_  512
#define B_  32
#define D_  512
#define FF_ 2048
#define L_  6
#define O_  1000
#define M_  (B_*S_)     // 16384 rows of activations
#define G_  256         // attention groups (buggy reshape semantics)
#define DH_ 64

typedef __attribute__((ext_vector_type(8))) short bf16x8;
typedef __attribute__((ext_vector_type(4))) float f32x4;
typedef __attribute__((ext_vector_type(16))) float f32x16;

__device__ __forceinline__ unsigned short f2bf(float f) {
  unsigned int u = __builtin_bit_cast(unsigned int, f);
  u = (u + 0x7fffu + ((u >> 16) & 1u)) >> 16;
  return (unsigned short)u;
}
__device__ __forceinline__ float bf2f(unsigned short u) {
  return __builtin_bit_cast(float, (unsigned int)u << 16);
}
__device__ __forceinline__ unsigned int pkbf(float a, float b) {
  return (unsigned int)f2bf(a) | ((unsigned int)f2bf(b) << 16);
}
// truncating pack of 2 floats -> 2 bf16 in one v_perm_b32 (hi16 of each)
__device__ __forceinline__ unsigned int prm(float a, float b) {
  return __builtin_amdgcn_perm(__builtin_bit_cast(unsigned int, b),
                               __builtin_bit_cast(unsigned int, a), 0x07060302u);
}
__device__ __forceinline__ void gload_lds16(const void* g, void* l) {
  __builtin_amdgcn_global_load_lds(
      (const __attribute__((address_space(1))) unsigned int*)g,
      (__attribute__((address_space(3))) unsigned int*)l, 16, 0, 0);
}

// ---------------- positional encoding table [512][512] f32 ----------------
__global__ void pe_kernel(float* __restrict__ pe) {
  int i = blockIdx.x * 256 + threadIdx.x;
  int s = i >> 9, d = i & 511;
  double de = (double)(d & ~1);
  double ang = (double)s * exp(de * (-9.210340371976184 / 512.0));
  pe[i] = (d & 1) ? (float)cos(ang) : (float)sin(ang);
}

// ------------- transpose-convert W [z][K][N] f32 -> Wt [z-stride ozs][N][K] bf16 -------------
__global__ void wconv_kernel(const float* __restrict__ W, unsigned short* __restrict__ Wt,
                             int K, int N, size_t ozs) {
  __shared__ float tile[32][33];
  const float* Wl = W + (size_t)blockIdx.z * K * N;
  unsigned short* Wtl = Wt + (size_t)blockIdx.z * ozs;
  int k0 = blockIdx.x * 32, n0 = blockIdx.y * 32;
  int c = threadIdx.x & 31, rb = threadIdx.x >> 5;
#pragma unroll
  for (int i = 0; i < 4; ++i) {
    int r = rb + i * 8;
    tile[r][c] = Wl[(size_t)(k0 + r) * N + n0 + c];
  }
  __syncthreads();
#pragma unroll
  for (int i = 0; i < 4; ++i) {
    int r = rb + i * 8;
    Wtl[(size_t)(n0 + r) * K + k0 + c] = f2bf(tile[c][r]);
  }
}

// ------------- embedding + PE (bf16 out only) -------------
__global__ void embed_kernel(const int* __restrict__ x, const float* __restrict__ emb,
                             const float* __restrict__ pe, unsigned short* __restrict__ xb) {
  int bi = blockIdx.x;            // s*B + b
  int s = bi / B_, b = bi % B_;
  int tok = x[s * B_ + b];
  int d = threadIdx.x * 4;
  float4 e = *(const float4*)(emb + (size_t)tok * D_ + d);
  float4 p = *(const float4*)(pe + (size_t)s * D_ + d);
  size_t o = ((size_t)b * S_ + s) * D_ + d;
  ushort4 u;
  u.x = f2bf(e.x + p.x); u.y = f2bf(e.y + p.y);
  u.z = f2bf(e.z + p.z); u.w = f2bf(e.w + p.w);
  *(ushort4*)(xb + o) = u;
}

// ------------- bf16 MFMA GEMM, 128x128 tile, BK=32, double-buffered, 3 wg/CU -------------
// acc = 64 VGPR -> 3 waves/SIMD; 12 waves/CU hide the barrier drain via TLP.
// split=1: N logical 1536, 128-col tile lies in one 512-col segment -> {o0,o1,o2}
__global__ __launch_bounds__(256, 3) void gemm128_kernel(
    const unsigned short* __restrict__ A, const unsigned short* __restrict__ Bt,
    const float* __restrict__ b0, const float* __restrict__ b1, const float* __restrict__ b2,
    unsigned short* __restrict__ o0, unsigned short* __restrict__ o1, unsigned short* __restrict__ o2,
    int K, int N, int relu, int split, int nbx) {
  __shared__ unsigned short As[2][128 * 32];   // 8 KB each
  __shared__ unsigned short Bs[2][128 * 32];   // 8 KB each -> 32 KB total
  int nwg = nbx * (M_ / 128);
  int cpx = nwg >> 3;
  int id = blockIdx.x;
  int wg = (id & 7) * cpx + (id >> 3);         // bijective: nwg % 8 == 0
  int bx = wg % nbx, by = wg / nbx;
  int m0 = by * 128, n0 = bx * 128;

  int tid = threadIdx.x, lane = tid & 63, wid = tid >> 6;
  int wm = wid >> 1, wn = wid & 1;
  f32x4 acc[4][4];
#pragma unroll
  for (int mi = 0; mi < 4; ++mi)
#pragma unroll
    for (int ni = 0; ni < 4; ++ni) acc[mi][ni] = (f32x4)0.0f;

  int srow = lane >> 2, scol = (lane & 3) * 8;
  const unsigned short* Abase = A + (size_t)m0 * K;
  const unsigned short* Bbase = Bt + (size_t)n0 * K;
  int c16 = lane & 15, hi = lane >> 4;
  int koff = hi * 8;
  int arow = wm * 64 + c16, brow = wn * 64 + c16;
  int nk = K >> 5;

  auto STAGE = [&](int kt, int bb) {
    int k0 = kt * 32;
#pragma unroll
    for (int i = 0; i < 2; ++i) {
      int c = wid * 2 + i;
      gload_lds16(Abase + (size_t)(c * 16 + srow) * K + k0 + scol, (char*)As[bb] + c * 1024);
      gload_lds16(Bbase + (size_t)(c * 16 + srow) * K + k0 + scol, (char*)Bs[bb] + c * 1024);
    }
  };

  STAGE(0, 0); STAGE(1, 1);
  int bb = 0;
  for (int kt = 0; kt < nk; ++kt) {
    if (kt + 1 < nk) asm volatile("s_waitcnt vmcnt(4)" ::: "memory");
    else             asm volatile("s_waitcnt vmcnt(0)" ::: "memory");
    __builtin_amdgcn_s_barrier();       // tile kt visible
    __builtin_amdgcn_sched_barrier(0);
    bf16x8 af[4], bfr[4];
#pragma unroll
    for (int mi = 0; mi < 4; ++mi) af[mi] = *(const bf16x8*)&As[bb][(arow + mi * 16) * 32 + koff];
#pragma unroll
    for (int ni = 0; ni < 4; ++ni) bfr[ni] = *(const bf16x8*)&Bs[bb][(brow + ni * 16) * 32 + koff];
    __builtin_amdgcn_s_setprio(1);
#pragma unroll
    for (int mi = 0; mi < 4; ++mi)
#pragma unroll
      for (int ni = 0; ni < 4; ++ni)
        acc[mi][ni] = __builtin_amdgcn_mfma_f32_16x16x32_bf16(bfr[ni], af[mi], acc[mi][ni], 0, 0, 0);
    __builtin_amdgcn_s_setprio(0);
    __builtin_amdgcn_sched_barrier(0);
    __builtin_amdgcn_s_barrier();       // all waves done reading buf bb
    if (kt + 2 < nk) STAGE(kt + 2, bb);
    bb ^= 1;
  }

  const float* bias = b0;
  unsigned short* outb = o0;
  int nbase = n0, ostride = N;
  if (split) {
    int seg = n0 >> 9;
    if (seg == 1) { bias = b1; outb = o1; }
    else if (seg == 2) { bias = b2; outb = o2; }
    nbase = n0 & 511; ostride = 512;
  }
#pragma unroll
  for (int ni = 0; ni < 4; ++ni) {
    int colb = nbase + wn * 64 + ni * 16 + hi * 4;
    float4 bv = *(const float4*)(bias + colb);
#pragma unroll
    for (int mi = 0; mi < 4; ++mi) {
      int row = m0 + wm * 64 + mi * 16 + c16;
      float v0 = acc[mi][ni][0] + bv.x;
      float v1 = acc[mi][ni][1] + bv.y;
      float v2 = acc[mi][ni][2] + bv.z;
      float v3 = acc[mi][ni][3] + bv.w;
      if (relu) { v0 = fmaxf(v0, 0.f); v1 = fmaxf(v1, 0.f); v2 = fmaxf(v2, 0.f); v3 = fmaxf(v3, 0.f); }
      *(uint2*)(outb + (size_t)row * ostride + colb) = make_uint2(pkbf(v0, v1), pkbf(v2, v3));
    }
  }
}

// ------------- fused add-residual + LayerNorm (bf16), 2 rows per block -------------
__global__ __launch_bounds__(256) void addln_kernel(
    const unsigned short* __restrict__ Y, const unsigned short* __restrict__ R,
    const float* __restrict__ g, const float* __restrict__ b,
    unsigned short* __restrict__ Out) {
  __shared__ float red[2][2], red2[2][2];
  int t = threadIdx.x;
  int rg = t >> 7;            // row within block (0..1)
  int tt = t & 127;
  int row = blockIdx.x * 2 + rg;
  size_t o = (size_t)row * 512 + tt * 4;
  ushort4 yv = *(const ushort4*)(Y + o);
  ushort4 rv = *(const ushort4*)(R + o);
  float v0 = bf2f(yv.x) + bf2f(rv.x);
  float v1 = bf2f(yv.y) + bf2f(rv.y);
  float v2 = bf2f(yv.z) + bf2f(rv.z);
  float v3 = bf2f(yv.w) + bf2f(rv.w);
  float s = v0 + v1 + v2 + v3;
#pragma unroll
  for (int m = 1; m < 64; m <<= 1) s += __shfl_xor(s, m);
  if ((tt & 63) == 0) red[rg][tt >> 6] = s;
  __syncthreads();
  float mean = (red[rg][0] + red[rg][1]) * (1.0f / 512.0f);
  float d0 = v0 - mean, d1 = v1 - mean, d2 = v2 - mean, d3 = v3 - mean;
  float sq = d0 * d0 + d1 * d1 + d2 * d2 + d3 * d3;
#pragma unroll
  for (int m = 1; m < 64; m <<= 1) sq += __shfl_xor(sq, m);
  if ((tt & 63) == 0) red2[rg][tt >> 6] = sq;
  __syncthreads();
  float var = (red2[rg][0] + red2[rg][1]) * (1.0f / 512.0f);
  float rstd = rsqrtf(var + 1e-5f);
  float4 gg = *(const float4*)(g + tt * 4);
  float4 bb = *(const float4*)(b + tt * 4);
  float y0 = d0 * rstd * gg.x + bb.x;
  float y1 = d1 * rstd * gg.y + bb.y;
  float y2 = d2 * rstd * gg.z + bb.z;
  float y3 = d3 * rstd * gg.w + bb.w;
  *(uint2*)(Out + o) = make_uint2(pkbf(y0, y1), pkbf(y2, y3));
}

// ------------- flash attention, 32x32 swapped-QK^T, in-register softmax -------------
// grid (2, 256): wave owns 64 q rows. T14 reg-staging + LDS double-buffer:
// ONE barrier per K-tile (buf[cur^1]'s last reads were ordered by the previous barrier).
__global__ __launch_bounds__(256) void attn_kernel(
    const unsigned short* __restrict__ Q, const unsigned short* __restrict__ Kb,
    const unsigned short* __restrict__ Vb, unsigned short* __restrict__ Ctx) {
  __shared__ char KlB[2][8192];   // K tile [64 k][64 d] bf16, XOR-swizzled rows
  __shared__ char VtB[2][8192];   // V^T tile [64 d][64 k] bf16, XOR-swizzled rows
  int g = blockIdx.y;
  int q0 = blockIdx.x * 256;
  const unsigned short* Kg = Kb + (size_t)g * 512 * 64;
  const unsigned short* Vg = Vb + (size_t)g * 512 * 64;
  int tid = threadIdx.x, lane = tid & 63, wid = tid >> 6;
  int l31 = lane & 31, h = lane >> 5;
  bool lo = (lane < 32);
  int qrowA = q0 + wid * 64 + l31;
  int qrowB = qrowA + 32;
  const float sc2 = 0.125f * 1.44269504f;

  bf16x8 qfa[4], qfb[4];
  {
    const unsigned short* qpa = Q + ((size_t)g * 512 + qrowA) * 64;
    const unsigned short* qpb = Q + ((size_t)g * 512 + qrowB) * 64;
#pragma unroll
    for (int c = 0; c < 4; ++c) {
      bf16x8 ra = *(const bf16x8*)(qpa + c * 16 + h * 8);
      bf16x8 rb = *(const bf16x8*)(qpb + c * 16 + h * 8);
      union { unsigned int u[4]; bf16x8 v; } ua, ub;
#pragma unroll
      for (int j = 0; j < 4; ++j) {
        ua.u[j] = pkbf(bf2f((unsigned short)ra[2 * j]) * sc2,
                       bf2f((unsigned short)ra[2 * j + 1]) * sc2);
        ub.u[j] = pkbf(bf2f((unsigned short)rb[2 * j]) * sc2,
                       bf2f((unsigned short)rb[2 * j + 1]) * sc2);
      }
      qfa[c] = ua.v; qfb[c] = ub.v;
    }
  }

  f32x16 cA0 = (f32x16)0.0f, cA1 = (f32x16)0.0f;
  f32x16 cB0 = (f32x16)0.0f, cB1 = (f32x16)0.0f;
  float mrA = -3.0e38f, lsA = 0.0f;
  float mrB = -3.0e38f, lsB = 0.0f;

  // staging geometry: thread covers row = tid>>2, two 16B chunks at byte cols cbA, cbA+64
  int rowS = tid >> 2;
  int cbA = (tid & 3) * 16;
  int cbB = cbA + 64;
  int swA = cbA ^ ((rowS & 7) << 4);
  int swB = cbB ^ ((rowS & 7) << 4);

  // prologue: tile 0 into regs
  bf16x8 kc0 = *(const bf16x8*)(Kg + (size_t)rowS * 64 + cbA / 2);
  bf16x8 kc1 = *(const bf16x8*)(Kg + (size_t)rowS * 64 + cbB / 2);
  bf16x8 vc0 = *(const bf16x8*)(Vg + (size_t)rowS * 64 + cbA / 2);
  bf16x8 vc1 = *(const bf16x8*)(Vg + (size_t)rowS * 64 + cbB / 2);

  int cur = 0;
  for (int kt = 0; kt < 8; ++kt) {
    // write current tile regs -> LDS[cur] (K swizzled rows; V transposed + swizzled)
    char* Kl = KlB[cur];
    char* Vt = VtB[cur];
    *(bf16x8*)(Kl + rowS * 128 + swA) = kc0;
    *(bf16x8*)(Kl + rowS * 128 + swB) = kc1;
#pragma unroll
    for (int j = 0; j < 8; ++j) {
      int dA = cbA / 2 + j;
      int dB = cbB / 2 + j;
      *(unsigned short*)(Vt + dA * 128 + ((2 * rowS) ^ ((dA & 7) << 4))) = (unsigned short)vc0[j];
      *(unsigned short*)(Vt + dB * 128 + ((2 * rowS) ^ ((dB & 7) << 4))) = (unsigned short)vc1[j];
    }
    // T14: issue next tile's global loads; they land during compute below
    bf16x8 kn0, kn1, vn0, vn1;
    if (kt < 7) {
      size_t nb = (size_t)((kt + 1) * 64 + rowS) * 64;
      kn0 = *(const bf16x8*)(Kg + nb + cbA / 2);
      kn1 = *(const bf16x8*)(Kg + nb + cbB / 2);
      vn0 = *(const bf16x8*)(Vg + nb + cbA / 2);
      vn1 = *(const bf16x8*)(Vg + nb + cbB / 2);
    }
    __syncthreads();   // staged tile visible; also orders last iter's reads of buf cur^1

#pragma unroll
    for (int sub = 0; sub < 2; ++sub) {
      f32x16 s0 = (f32x16)0.0f, s1 = (f32x16)0.0f;
#pragma unroll
      for (int c = 0; c < 4; ++c) {
        int cb = 32 * c + 16 * h;
        int sw = cb ^ ((l31 & 7) << 4);
        bf16x8 k0 = *(const bf16x8*)(Kl + l31 * 128 + sw);
        bf16x8 k1 = *(const bf16x8*)(Kl + (32 + l31) * 128 + sw);
        bf16x8 qf = sub ? qfb[c] : qfa[c];
        s0 = __builtin_amdgcn_mfma_f32_32x32x16_bf16(k0, qf, s0, 0, 0, 0);
        s1 = __builtin_amdgcn_mfma_f32_32x32x16_bf16(k1, qf, s1, 0, 0, 0);
      }

      float mr = sub ? mrB : mrA;
      float ls = sub ? lsB : lsA;
      float pm = s0[0];
#pragma unroll
      for (int i = 1; i < 16; ++i) pm = fmaxf(pm, s0[i]);
#pragma unroll
      for (int i = 0; i < 16; ++i) pm = fmaxf(pm, s1[i]);
      pm = fmaxf(pm, __shfl_xor(pm, 32));
      // T13 defer-max
      if (!__all(pm <= mr + 8.0f)) {
        float mnew = fmaxf(mr, pm);
        float alpha = exp2f(mr - mnew);
        ls *= alpha;
        if (sub) {
#pragma unroll
          for (int i = 0; i < 16; ++i) { cB0[i] *= alpha; cB1[i] *= alpha; }
        } else {
#pragma unroll
          for (int i = 0; i < 16; ++i) { cA0[i] *= alpha; cA1[i] *= alpha; }
        }
        mr = mnew;
      }
      float p[32];
      float rs = 0.0f;
#pragma unroll
      for (int i = 0; i < 16; ++i) { p[i] = exp2f(s0[i] - mr); rs += p[i]; }
#pragma unroll
      for (int i = 0; i < 16; ++i) { p[16 + i] = exp2f(s1[i] - mr); rs += p[16 + i]; }
      float rso = __shfl_xor(rs, 32);
      ls += rs + rso;
      if (sub) { mrB = mr; lsB = ls; } else { mrA = mr; lsA = ls; }

      union { unsigned int u[4]; bf16x8 v; } pa[4];
#pragma unroll
      for (int t = 0; t < 2; ++t) {
#pragma unroll
        for (int u = 0; u < 2; ++u) {
#pragma unroll
          for (int pr = 0; pr < 2; ++pr) {
            const int b0i = t * 16 + 8 * u;
            unsigned int a  = prm(p[b0i + 2 * pr],     p[b0i + 2 * pr + 1]);
            unsigned int b  = prm(p[b0i + 4 + 2 * pr], p[b0i + 4 + 2 * pr + 1]);
            unsigned int sa = __shfl_xor(a, 32);
            unsigned int sb = __shfl_xor(b, 32);
            pa[t * 2 + u].u[pr]     = lo ? a  : sb;
            pa[t * 2 + u].u[2 + pr] = lo ? sa : b;
          }
        }
      }

#pragma unroll
      for (int kc = 0; kc < 4; ++kc) {
        int cb = 32 * kc + 16 * h;
        int sw = cb ^ ((l31 & 7) << 4);
        bf16x8 v0 = *(const bf16x8*)(Vt + l31 * 128 + sw);
        bf16x8 v1 = *(const bf16x8*)(Vt + (32 + l31) * 128 + sw);
        if (sub) {
          cB0 = __builtin_amdgcn_mfma_f32_32x32x16_bf16(v0, pa[kc].v, cB0, 0, 0, 0);
          cB1 = __builtin_amdgcn_mfma_f32_32x32x16_bf16(v1, pa[kc].v, cB1, 0, 0, 0);
        } else {
          cA0 = __builtin_amdgcn_mfma_f32_32x32x16_bf16(v0, pa[kc].v, cA0, 0, 0, 0);
          cA1 = __builtin_amdgcn_mfma_f32_32x32x16_bf16(v1, pa[kc].v, cA1, 0, 0, 0);
        }
      }
    }

    if (kt < 7) { kc0 = kn0; kc1 = kn1; vc0 = vn0; vc1 = vn1; }
    cur ^= 1;
  }

#pragma unroll
  for (int sub = 0; sub < 2; ++sub) {
    float inv = 1.0f / (sub ? lsB : lsA);
    int qrow = sub ? qrowB : qrowA;
    unsigned short* cp = Ctx + ((size_t)g * 512 + qrow) * 64;
#pragma unroll
    for (int dh = 0; dh < 2; ++dh) {
#pragma unroll
      for (int rq = 0; rq < 4; ++rq) {
        float e0 = (sub ? (dh ? cB1[rq * 4 + 0] : cB0[rq * 4 + 0]) : (dh ? cA1[rq * 4 + 0] : cA0[rq * 4 + 0])) * inv;
        float e1 = (sub ? (dh ? cB1[rq * 4 + 1] : cB0[rq * 4 + 1]) : (dh ? cA1[rq * 4 + 1] : cA0[rq * 4 + 1])) * inv;
        float e2 = (sub ? (dh ? cB1[rq * 4 + 2] : cB0[rq * 4 + 2]) : (dh ? cA1[rq * 4 + 2] : cA0[rq * 4 + 2])) * inv;
        float e3 = (sub ? (dh ? cB1[rq * 4 + 3] : cB0[rq * 4 + 3]) : (dh ? cA1[rq * 4 + 3] : cA0[rq * 4 + 3])) * inv;
        int d0 = dh * 32 + rq * 8 + h * 4;
        *(uint2*)(cp + d0) = make_uint2(pkbf(e0, e1), pkbf(e2, e3));
      }
    }
  }
}

// ------------- final FC: out[32][1000] = act[32][262144](bf16) @ Wfc + bfc (split-K) -------------
#define KCH 1024
__global__ __launch_bounds__(512) void fc_part_kernel(const unsigned short* __restrict__ act,
                                                      const float* __restrict__ Wfc,
                                                      float* __restrict__ part) {
  __shared__ float al[32][256];
  int t = threadIdx.x;
  int kc = blockIdx.x;
  size_t k0 = (size_t)kc * KCH;
  int o1 = t;               // < 1000 always
  int o2 = 512 + t;
  bool a2 = (o2 < O_);
  float acc1[32], acc2[32];
#pragma unroll
  for (int bb = 0; bb < 32; ++bb) { acc1[bb] = 0.0f; acc2[bb] = 0.0f; }
  for (int sub = 0; sub < KCH / 256; ++sub) {
    __syncthreads();
    for (int i = t; i < 32 * 128; i += 512) {
      int bb = i >> 7, kk = (i & 127) * 2;
      ushort2 u = *(const ushort2*)(act + (size_t)bb * 262144 + k0 + sub * 256 + kk);
      al[bb][kk] = bf2f(u.x);
      al[bb][kk + 1] = bf2f(u.y);
    }
    __syncthreads();
    const float* wp = Wfc + (k0 + sub * 256) * O_;
    for (int kk = 0; kk < 256; kk += 4) {
      const float* wr = wp + (size_t)kk * O_;
      float w10 = wr[o1];
      float w11 = wr[O_ + o1];
      float w12 = wr[2 * O_ + o1];
      float w13 = wr[3 * O_ + o1];
      float w20 = a2 ? wr[o2] : 0.0f;
      float w21 = a2 ? wr[O_ + o2] : 0.0f;
      float w22 = a2 ? wr[2 * O_ + o2] : 0.0f;
      float w23 = a2 ? wr[3 * O_ + o2] : 0.0f;
#pragma unroll
      for (int bb = 0; bb < 32; ++bb) {
        f32x4 av = *(const f32x4*)&al[bb][kk];
        acc1[bb] = fmaf(av[0], w10, acc1[bb]);
        acc1[bb] = fmaf(av[1], w11, acc1[bb]);
        acc1[bb] = fmaf(av[2], w12, acc1[bb]);
        acc1[bb] = fmaf(av[3], w13, acc1[bb]);
        acc2[bb] = fmaf(av[0], w20, acc2[bb]);
        acc2[bb] = fmaf(av[1], w21, acc2[bb]);
        acc2[bb] = fmaf(av[2], w22, acc2[bb]);
        acc2[bb] = fmaf(av[3], w23, acc2[bb]);
      }
    }
  }
#pragma unroll
  for (int bb = 0; bb < 32; ++bb) {
    part[((size_t)kc * 32 + bb) * O_ + o1] = acc1[bb];
    if (a2) part[((size_t)kc * 32 + bb) * O_ + o2] = acc2[bb];
  }
}

__global__ void fc_reduce_kernel(const float* __restrict__ part, const float* __restrict__ bfc,
                                 float* __restrict__ out) {
  int o = blockIdx.x * 256 + threadIdx.x;
  int b = blockIdx.y;
  if (o >= O_) return;
  float s = bfc[o];
  for (int c = 0; c < 256; ++c) s += part[((size_t)c * 32 + b) * O_ + o];
  out[(size_t)b * O_ + o] = s;
}

extern "C" void kernel_launch(void* const* d_in, const int* in_sizes, int n_in,
                              void* d_out, int out_size, void* d_ws, size_t ws_size,
                              hipStream_t stream) {
  const int*   x   = (const int*)d_in[0];
  const float* emb = (const float*)d_in[2];
  const float* Wq  = (const float*)d_in[3];
  const float* bq  = (const float*)d_in[4];
  const float* Wk  = (const float*)d_in[5];
  const float* bk  = (const float*)d_in[6];
  const float* Wv  = (const float*)d_in[7];
  const float* bv  = (const float*)d_in[8];
  const float* Wo  = (const float*)d_in[9];
  const float* bo  = (const float*)d_in[10];
  const float* g1  = (const float*)d_in[11];
  const float* bn1 = (const float*)d_in[12];
  const float* W1  = (const float*)d_in[13];
  const float* bf1 = (const float*)d_in[14];
  const float* W2  = (const float*)d_in[15];
  const float* bf2 = (const float*)d_in[16];
  const float* g2  = (const float*)d_in[17];
  const float* bn2 = (const float*)d_in[18];
  const float* Wfc = (const float*)d_in[19];
  const float* bfc = (const float*)d_in[20];
  float* out = (float*)d_out;

  char* ws = (char*)d_ws;
  size_t off = 0;
  auto take = [&](size_t bytes) { char* p = ws + off; off += (bytes + 255) & ~(size_t)255; return p; };
  float*          pe   = (float*)take((size_t)512 * 512 * 4);
  unsigned short* wqkv = (unsigned short*)take((size_t)L_ * 1536 * 512 * 2);
  unsigned short* wot  = (unsigned short*)take((size_t)L_ * 512 * 512 * 2);
  unsigned short* w1t  = (unsigned short*)take((size_t)L_ * 2048 * 512 * 2);
  unsigned short* w2t  = (unsigned short*)take((size_t)L_ * 512 * 2048 * 2);
  unsigned short* xb   = (unsigned short*)take((size_t)M_ * 512 * 2);
  unsigned short* qb   = (unsigned short*)take((size_t)M_ * 512 * 2);
  unsigned short* kb   = (unsigned short*)take((size_t)M_ * 512 * 2);
  unsigned short* vb   = (unsigned short*)take((size_t)M_ * 512 * 2);
  unsigned short* cxb  = (unsigned short*)take((size_t)M_ * 512 * 2);
  unsigned short* hb   = (unsigned short*)take((size_t)M_ * 512 * 2);
  unsigned short* t1   = (unsigned short*)take((size_t)M_ * 512 * 2);
  unsigned short* f1b  = qb;          // alias: q/k/v/cxb region (67 MB contiguous) free during FFN
  float*          part = (float*)qb;  // alias: free after last layer (needs 32.8 MB)

  pe_kernel<<<1024, 256, 0, stream>>>(pe);
  wconv_kernel<<<dim3(16, 16, L_), 256, 0, stream>>>(Wq, wqkv,          512, 512,  (size_t)1536 * 512);
  wconv_kernel<<<dim3(16, 16, L_), 256, 0, stream>>>(Wk, wqkv + 262144, 512, 512,  (size_t)1536 * 512);
  wconv_kernel<<<dim3(16, 16, L_), 256, 0, stream>>>(Wv, wqkv + 524288, 512, 512,  (size_t)1536 * 512);
  wconv_kernel<<<dim3(16, 16, L_), 256, 0, stream>>>(Wo, wot,           512, 512,  (size_t)512 * 512);
  wconv_kernel<<<dim3(16, 64, L_), 256, 0, stream>>>(W1, w1t,           512, 2048, (size_t)2048 * 512);
  wconv_kernel<<<dim3(64, 16, L_), 256, 0, stream>>>(W2, w2t,           2048, 512, (size_t)512 * 2048);
  embed_kernel<<<M_, 128, 0, stream>>>(x, emb, pe, xb);

  for (int l = 0; l < L_; ++l) {
    // QKV: N=1536 -> nbx=12, grid 1536
    gemm128_kernel<<<1536, 256, 0, stream>>>(
        xb, wqkv + (size_t)l * 1536 * 512,
        bq + l * 512, bk + l * 512, bv + l * 512,
        qb, kb, vb, 512, 1536, 0, 1, 12);
    attn_kernel<<<dim3(2, G_), 256, 0, stream>>>(qb, kb, vb, cxb);
    // O-proj: N=512 -> nbx=4, grid 512
    gemm128_kernel<<<512, 256, 0, stream>>>(
        cxb, wot + (size_t)l * 512 * 512,
        bo + l * 512, nullptr, nullptr,
        t1, nullptr, nullptr, 512, 512, 0, 0, 4);
    addln_kernel<<<M_ / 2, 256, 0, stream>>>(t1, xb, g1 + l * 512, bn1 + l * 512, hb);
    // FF1: N=2048 -> nbx=16, grid 2048
    gemm128_kernel<<<2048, 256, 0, stream>>>(
        hb, w1t + (size_t)l * 2048 * 512,
        bf1 + l * 2048, nullptr, nullptr,
        f1b, nullptr, nullptr, 512, 2048, 1, 0, 16);
    // FF2: N=512, K=2048 -> nbx=4, grid 512
    gemm128_kernel<<<512, 256, 0, stream>>>(
        f1b, w2t + (size_t)l * 512 * 2048,
        bf2 + l * 512, nullptr, nullptr,
        t1, nullptr, nullptr, 2048, 512, 0, 0, 4);
    addln_kernel<<<M_ / 2, 256, 0, stream>>>(t1, hb, g2 + l * 512, bn2 + l * 512, xb);
  }

  fc_part_kernel<<<256, 512, 0, stream>>>(xb, Wfc, part);
  fc_reduce_kernel<<<dim3(4, 32), 256, 0, stream>>>(part, bfc, out);
}

// Round 13
// 1772.232 us; speedup vs baseline: 1.1329x; 1.0473x over previous
//
#include <hip/hip_runtime.h>
#include <cstdint>
#include <cstddef>

#define S_  512
#define B_  32
#define D_  512
#define FF_ 2048
#define L_  6
#define O_  1000
#define M_  (B_*S_)     // 16384 rows of activations
#define G_  256         // attention groups (buggy reshape semantics)
#define DH_ 64

typedef __attribute__((ext_vector_type(8))) short bf16x8;
typedef __attribute__((ext_vector_type(4))) float f32x4;
typedef __attribute__((ext_vector_type(16))) float f32x16;

__device__ __forceinline__ unsigned short f2bf(float f) {
  unsigned int u = __builtin_bit_cast(unsigned int, f);
  u = (u + 0x7fffu + ((u >> 16) & 1u)) >> 16;
  return (unsigned short)u;
}
__device__ __forceinline__ float bf2f(unsigned short u) {
  return __builtin_bit_cast(float, (unsigned int)u << 16);
}
__device__ __forceinline__ unsigned int pkbf(float a, float b) {
  return (unsigned int)f2bf(a) | ((unsigned int)f2bf(b) << 16);
}
// truncating pack of 2 floats -> 2 bf16 in one v_perm_b32 (hi16 of each)
__device__ __forceinline__ unsigned int prm(float a, float b) {
  return __builtin_amdgcn_perm(__builtin_bit_cast(unsigned int, b),
                               __builtin_bit_cast(unsigned int, a), 0x07060302u);
}
__device__ __forceinline__ void gload_lds16(const void* g, void* l) {
  __builtin_amdgcn_global_load_lds(
      (const __attribute__((address_space(1))) unsigned int*)g,
      (__attribute__((address_space(3))) unsigned int*)l, 16, 0, 0);
}

// ---------------- positional encoding table [512][512] f32 ----------------
__global__ void pe_kernel(float* __restrict__ pe) {
  int i = blockIdx.x * 256 + threadIdx.x;
  int s = i >> 9, d = i & 511;
  double de = (double)(d & ~1);
  double ang = (double)s * exp(de * (-9.210340371976184 / 512.0));
  pe[i] = (d & 1) ? (float)cos(ang) : (float)sin(ang);
}

// ------------- transpose-convert W [z][K][N] f32 -> Wt [z-stride ozs][N][K] bf16 -------------
__global__ void wconv_kernel(const float* __restrict__ W, unsigned short* __restrict__ Wt,
                             int K, int N, size_t ozs) {
  __shared__ float tile[32][33];
  const float* Wl = W + (size_t)blockIdx.z * K * N;
  unsigned short* Wtl = Wt + (size_t)blockIdx.z * ozs;
  int k0 = blockIdx.x * 32, n0 = blockIdx.y * 32;
  int c = threadIdx.x & 31, rb = threadIdx.x >> 5;
#pragma unroll
  for (int i = 0; i < 4; ++i) {
    int r = rb + i * 8;
    tile[r][c] = Wl[(size_t)(k0 + r) * N + n0 + c];
  }
  __syncthreads();
#pragma unroll
  for (int i = 0; i < 4; ++i) {
    int r = rb + i * 8;
    Wtl[(size_t)(n0 + r) * K + k0 + c] = f2bf(tile[c][r]);
  }
}

// ------------- embedding + PE (bf16 out only) -------------
__global__ void embed_kernel(const int* __restrict__ x, const float* __restrict__ emb,
                             const float* __restrict__ pe, unsigned short* __restrict__ xb) {
  int bi = blockIdx.x;            // s*B + b
  int s = bi / B_, b = bi % B_;
  int tok = x[s * B_ + b];
  int d = threadIdx.x * 4;
  float4 e = *(const float4*)(emb + (size_t)tok * D_ + d);
  float4 p = *(const float4*)(pe + (size_t)s * D_ + d);
  size_t o = ((size_t)b * S_ + s) * D_ + d;
  ushort4 u;
  u.x = f2bf(e.x + p.x); u.y = f2bf(e.y + p.y);
  u.z = f2bf(e.z + p.z); u.w = f2bf(e.w + p.w);
  *(ushort4*)(xb + o) = u;
}

// ------------- bf16 MFMA GEMM, 128x128 tile, BK=32, triple-buffered, 3 wg/CU -------------
// acc = 64 VGPR -> 3 waves/SIMD; 48 KB LDS -> 3 wg/CU; vmcnt(8) keeps 2 tiles in flight.
// split=1: N logical 1536, 128-col tile lies in one 512-col segment -> {o0,o1,o2}
__global__ __launch_bounds__(256, 3) void gemm128_kernel(
    const unsigned short* __restrict__ A, const unsigned short* __restrict__ Bt,
    const float* __restrict__ b0, const float* __restrict__ b1, const float* __restrict__ b2,
    unsigned short* __restrict__ o0, unsigned short* __restrict__ o1, unsigned short* __restrict__ o2,
    int K, int N, int relu, int split, int nbx) {
  __shared__ unsigned short As[3][128 * 32];   // 8 KB each
  __shared__ unsigned short Bs[3][128 * 32];   // 8 KB each -> 48 KB total
  int nwg = nbx * (M_ / 128);
  int cpx = nwg >> 3;
  int id = blockIdx.x;
  int wg = (id & 7) * cpx + (id >> 3);         // bijective: nwg % 8 == 0
  int bx = wg % nbx, by = wg / nbx;
  int m0 = by * 128, n0 = bx * 128;

  int tid = threadIdx.x, lane = tid & 63, wid = tid >> 6;
  int wm = wid >> 1, wn = wid & 1;
  f32x4 acc[4][4];
#pragma unroll
  for (int mi = 0; mi < 4; ++mi)
#pragma unroll
    for (int ni = 0; ni < 4; ++ni) acc[mi][ni] = (f32x4)0.0f;

  int srow = lane >> 2, scol = (lane & 3) * 8;
  const unsigned short* Abase = A + (size_t)m0 * K;
  const unsigned short* Bbase = Bt + (size_t)n0 * K;
  int c16 = lane & 15, hi = lane >> 4;
  int koff = hi * 8;
  int arow = wm * 64 + c16, brow = wn * 64 + c16;
  int nk = K >> 5;

  auto STAGE = [&](int kt, int bb) {
    int k0 = kt * 32;
#pragma unroll
    for (int i = 0; i < 2; ++i) {
      int c = wid * 2 + i;
      gload_lds16(Abase + (size_t)(c * 16 + srow) * K + k0 + scol, (char*)As[bb] + c * 1024);
      gload_lds16(Bbase + (size_t)(c * 16 + srow) * K + k0 + scol, (char*)Bs[bb] + c * 1024);
    }
  };

  STAGE(0, 0); STAGE(1, 1); STAGE(2, 2);
  int bb = 0;
  for (int kt = 0; kt < nk; ++kt) {
    int rem = nk - 1 - kt;
    if (rem >= 2)      asm volatile("s_waitcnt vmcnt(8)" ::: "memory");
    else if (rem == 1) asm volatile("s_waitcnt vmcnt(4)" ::: "memory");
    else               asm volatile("s_waitcnt vmcnt(0)" ::: "memory");
    __builtin_amdgcn_s_barrier();       // tile kt visible
    __builtin_amdgcn_sched_barrier(0);
    bf16x8 af[4], bfr[4];
#pragma unroll
    for (int mi = 0; mi < 4; ++mi) af[mi] = *(const bf16x8*)&As[bb][(arow + mi * 16) * 32 + koff];
#pragma unroll
    for (int ni = 0; ni < 4; ++ni) bfr[ni] = *(const bf16x8*)&Bs[bb][(brow + ni * 16) * 32 + koff];
    __builtin_amdgcn_s_setprio(1);
#pragma unroll
    for (int mi = 0; mi < 4; ++mi)
#pragma unroll
      for (int ni = 0; ni < 4; ++ni)
        acc[mi][ni] = __builtin_amdgcn_mfma_f32_16x16x32_bf16(bfr[ni], af[mi], acc[mi][ni], 0, 0, 0);
    __builtin_amdgcn_s_setprio(0);
    __builtin_amdgcn_sched_barrier(0);
    __builtin_amdgcn_s_barrier();       // all waves done reading buf bb
    if (kt + 3 < nk) STAGE(kt + 3, bb);
    bb = (bb == 2) ? 0 : bb + 1;
  }

  const float* bias = b0;
  unsigned short* outb = o0;
  int nbase = n0, ostride = N;
  if (split) {
    int seg = n0 >> 9;
    if (seg == 1) { bias = b1; outb = o1; }
    else if (seg == 2) { bias = b2; outb = o2; }
    nbase = n0 & 511; ostride = 512;
  }
#pragma unroll
  for (int ni = 0; ni < 4; ++ni) {
    int colb = nbase + wn * 64 + ni * 16 + hi * 4;
    float4 bv = *(const float4*)(bias + colb);
#pragma unroll
    for (int mi = 0; mi < 4; ++mi) {
      int row = m0 + wm * 64 + mi * 16 + c16;
      float v0 = acc[mi][ni][0] + bv.x;
      float v1 = acc[mi][ni][1] + bv.y;
      float v2 = acc[mi][ni][2] + bv.z;
      float v3 = acc[mi][ni][3] + bv.w;
      if (relu) { v0 = fmaxf(v0, 0.f); v1 = fmaxf(v1, 0.f); v2 = fmaxf(v2, 0.f); v3 = fmaxf(v3, 0.f); }
      *(uint2*)(outb + (size_t)row * ostride + colb) = make_uint2(pkbf(v0, v1), pkbf(v2, v3));
    }
  }
}

// ------------- fused add-residual + LayerNorm, 1 row per wave (no LDS, no barriers) -------------
// 256 thr = 4 waves = 4 rows/block; lane handles 8 elements; grid = M/4
__global__ __launch_bounds__(256) void addln_kernel(
    const unsigned short* __restrict__ Y, const unsigned short* __restrict__ R,
    const float* __restrict__ g, const float* __restrict__ b,
    unsigned short* __restrict__ Out) {
  int lane = threadIdx.x & 63, w = threadIdx.x >> 6;
  int row = blockIdx.x * 4 + w;
  size_t o = (size_t)row * 512 + lane * 8;
  bf16x8 yv = *(const bf16x8*)(Y + o);
  bf16x8 rv = *(const bf16x8*)(R + o);
  float v[8];
#pragma unroll
  for (int j = 0; j < 8; ++j)
    v[j] = bf2f((unsigned short)yv[j]) + bf2f((unsigned short)rv[j]);
  float s = 0.0f;
#pragma unroll
  for (int j = 0; j < 8; ++j) s += v[j];
#pragma unroll
  for (int m = 1; m < 64; m <<= 1) s += __shfl_xor(s, m);
  float mean = s * (1.0f / 512.0f);
  float sq = 0.0f;
#pragma unroll
  for (int j = 0; j < 8; ++j) { float d = v[j] - mean; sq += d * d; }
#pragma unroll
  for (int m = 1; m < 64; m <<= 1) sq += __shfl_xor(sq, m);
  float rstd = rsqrtf(sq * (1.0f / 512.0f) + 1e-5f);
  float4 g0 = *(const float4*)(g + lane * 8);
  float4 g1 = *(const float4*)(g + lane * 8 + 4);
  float4 b0 = *(const float4*)(b + lane * 8);
  float4 b1 = *(const float4*)(b + lane * 8 + 4);
  float y0 = (v[0] - mean) * rstd * g0.x + b0.x;
  float y1 = (v[1] - mean) * rstd * g0.y + b0.y;
  float y2 = (v[2] - mean) * rstd * g0.z + b0.z;
  float y3 = (v[3] - mean) * rstd * g0.w + b0.w;
  float y4 = (v[4] - mean) * rstd * g1.x + b1.x;
  float y5 = (v[5] - mean) * rstd * g1.y + b1.y;
  float y6 = (v[6] - mean) * rstd * g1.z + b1.z;
  float y7 = (v[7] - mean) * rstd * g1.w + b1.w;
  uint4 u;
  u.x = pkbf(y0, y1); u.y = pkbf(y2, y3);
  u.z = pkbf(y4, y5); u.w = pkbf(y6, y7);
  *(uint4*)(Out + o) = u;
}

// ------------- flash attention, 32x32 swapped-QK^T, in-register softmax -------------
// grid (2, 256): wave owns 64 q rows. T14 reg-staging + LDS double-buffer, one barrier/tile.
__global__ __launch_bounds__(256) void attn_kernel(
    const unsigned short* __restrict__ Q, const unsigned short* __restrict__ Kb,
    const unsigned short* __restrict__ Vb, unsigned short* __restrict__ Ctx) {
  __shared__ char KlB[2][8192];   // K tile [64 k][64 d] bf16, XOR-swizzled rows
  __shared__ char VtB[2][8192];   // V^T tile [64 d][64 k] bf16, XOR-swizzled rows
  int g = blockIdx.y;
  int q0 = blockIdx.x * 256;
  const unsigned short* Kg = Kb + (size_t)g * 512 * 64;
  const unsigned short* Vg = Vb + (size_t)g * 512 * 64;
  int tid = threadIdx.x, lane = tid & 63, wid = tid >> 6;
  int l31 = lane & 31, h = lane >> 5;
  bool lo = (lane < 32);
  int qrowA = q0 + wid * 64 + l31;
  int qrowB = qrowA + 32;
  const float sc2 = 0.125f * 1.44269504f;

  bf16x8 qfa[4], qfb[4];
  {
    const unsigned short* qpa = Q + ((size_t)g * 512 + qrowA) * 64;
    const unsigned short* qpb = Q + ((size_t)g * 512 + qrowB) * 64;
#pragma unroll
    for (int c = 0; c < 4; ++c) {
      bf16x8 ra = *(const bf16x8*)(qpa + c * 16 + h * 8);
      bf16x8 rb = *(const bf16x8*)(qpb + c * 16 + h * 8);
      union { unsigned int u[4]; bf16x8 v; } ua, ub;
#pragma unroll
      for (int j = 0; j < 4; ++j) {
        ua.u[j] = pkbf(bf2f((unsigned short)ra[2 * j]) * sc2,
                       bf2f((unsigned short)ra[2 * j + 1]) * sc2);
        ub.u[j] = pkbf(bf2f((unsigned short)rb[2 * j]) * sc2,
                       bf2f((unsigned short)rb[2 * j + 1]) * sc2);
      }
      qfa[c] = ua.v; qfb[c] = ub.v;
    }
  }

  f32x16 cA0 = (f32x16)0.0f, cA1 = (f32x16)0.0f;
  f32x16 cB0 = (f32x16)0.0f, cB1 = (f32x16)0.0f;
  float mrA = -3.0e38f, lsA = 0.0f;
  float mrB = -3.0e38f, lsB = 0.0f;

  // staging geometry: thread covers row = tid>>2, two 16B chunks at byte cols cbA, cbA+64
  int rowS = tid >> 2;
  int cbA = (tid & 3) * 16;
  int cbB = cbA + 64;
  int swA = cbA ^ ((rowS & 7) << 4);
  int swB = cbB ^ ((rowS & 7) << 4);

  // prologue: tile 0 into regs
  bf16x8 kc0 = *(const bf16x8*)(Kg + (size_t)rowS * 64 + cbA / 2);
  bf16x8 kc1 = *(const bf16x8*)(Kg + (size_t)rowS * 64 + cbB / 2);
  bf16x8 vc0 = *(const bf16x8*)(Vg + (size_t)rowS * 64 + cbA / 2);
  bf16x8 vc1 = *(const bf16x8*)(Vg + (size_t)rowS * 64 + cbB / 2);

  int cur = 0;
  for (int kt = 0; kt < 8; ++kt) {
    // write current tile regs -> LDS[cur] (K swizzled rows; V transposed + swizzled)
    char* Kl = KlB[cur];
    char* Vt = VtB[cur];
    *(bf16x8*)(Kl + rowS * 128 + swA) = kc0;
    *(bf16x8*)(Kl + rowS * 128 + swB) = kc1;
#pragma unroll
    for (int j = 0; j < 8; ++j) {
      int dA = cbA / 2 + j;
      int dB = cbB / 2 + j;
      *(unsigned short*)(Vt + dA * 128 + ((2 * rowS) ^ ((dA & 7) << 4))) = (unsigned short)vc0[j];
      *(unsigned short*)(Vt + dB * 128 + ((2 * rowS) ^ ((dB & 7) << 4))) = (unsigned short)vc1[j];
    }
    // T14: issue next tile's global loads; they land during compute below
    bf16x8 kn0, kn1, vn0, vn1;
    if (kt < 7) {
      size_t nb = (size_t)((kt + 1) * 64 + rowS) * 64;
      kn0 = *(const bf16x8*)(Kg + nb + cbA / 2);
      kn1 = *(const bf16x8*)(Kg + nb + cbB / 2);
      vn0 = *(const bf16x8*)(Vg + nb + cbA / 2);
      vn1 = *(const bf16x8*)(Vg + nb + cbB / 2);
    }
    __syncthreads();   // staged tile visible; also orders last iter's reads of buf cur^1

#pragma unroll
    for (int sub = 0; sub < 2; ++sub) {
      f32x16 s0 = (f32x16)0.0f, s1 = (f32x16)0.0f;
#pragma unroll
      for (int c = 0; c < 4; ++c) {
        int cb = 32 * c + 16 * h;
        int sw = cb ^ ((l31 & 7) << 4);
        bf16x8 k0 = *(const bf16x8*)(Kl + l31 * 128 + sw);
        bf16x8 k1 = *(const bf16x8*)(Kl + (32 + l31) * 128 + sw);
        bf16x8 qf = sub ? qfb[c] : qfa[c];
        s0 = __builtin_amdgcn_mfma_f32_32x32x16_bf16(k0, qf, s0, 0, 0, 0);
        s1 = __builtin_amdgcn_mfma_f32_32x32x16_bf16(k1, qf, s1, 0, 0, 0);
      }

      float mr = sub ? mrB : mrA;
      float ls = sub ? lsB : lsA;
      float pm = s0[0];
#pragma unroll
      for (int i = 1; i < 16; ++i) pm = fmaxf(pm, s0[i]);
#pragma unroll
      for (int i = 0; i < 16; ++i) pm = fmaxf(pm, s1[i]);
      pm = fmaxf(pm, __shfl_xor(pm, 32));
      // T13 defer-max
      if (!__all(pm <= mr + 8.0f)) {
        float mnew = fmaxf(mr, pm);
        float alpha = exp2f(mr - mnew);
        ls *= alpha;
        if (sub) {
#pragma unroll
          for (int i = 0; i < 16; ++i) { cB0[i] *= alpha; cB1[i] *= alpha; }
        } else {
#pragma unroll
          for (int i = 0; i < 16; ++i) { cA0[i] *= alpha; cA1[i] *= alpha; }
        }
        mr = mnew;
      }
      float p[32];
      float rs = 0.0f;
#pragma unroll
      for (int i = 0; i < 16; ++i) { p[i] = exp2f(s0[i] - mr); rs += p[i]; }
#pragma unroll
      for (int i = 0; i < 16; ++i) { p[16 + i] = exp2f(s1[i] - mr); rs += p[16 + i]; }
      float rso = __shfl_xor(rs, 32);
      ls += rs + rso;
      if (sub) { mrB = mr; lsB = ls; } else { mrA = mr; lsA = ls; }

      union { unsigned int u[4]; bf16x8 v; } pa[4];
#pragma unroll
      for (int t = 0; t < 2; ++t) {
#pragma unroll
        for (int u = 0; u < 2; ++u) {
#pragma unroll
          for (int pr = 0; pr < 2; ++pr) {
            const int b0i = t * 16 + 8 * u;
            unsigned int a  = prm(p[b0i + 2 * pr],     p[b0i + 2 * pr + 1]);
            unsigned int b  = prm(p[b0i + 4 + 2 * pr], p[b0i + 4 + 2 * pr + 1]);
            unsigned int sa = __shfl_xor(a, 32);
            unsigned int sb = __shfl_xor(b, 32);
            pa[t * 2 + u].u[pr]     = lo ? a  : sb;
            pa[t * 2 + u].u[2 + pr] = lo ? sa : b;
          }
        }
      }

#pragma unroll
      for (int kc = 0; kc < 4; ++kc) {
        int cb = 32 * kc + 16 * h;
        int sw = cb ^ ((l31 & 7) << 4);
        bf16x8 v0 = *(const bf16x8*)(Vt + l31 * 128 + sw);
        bf16x8 v1 = *(const bf16x8*)(Vt + (32 + l31) * 128 + sw);
        if (sub) {
          cB0 = __builtin_amdgcn_mfma_f32_32x32x16_bf16(v0, pa[kc].v, cB0, 0, 0, 0);
          cB1 = __builtin_amdgcn_mfma_f32_32x32x16_bf16(v1, pa[kc].v, cB1, 0, 0, 0);
        } else {
          cA0 = __builtin_amdgcn_mfma_f32_32x32x16_bf16(v0, pa[kc].v, cA0, 0, 0, 0);
          cA1 = __builtin_amdgcn_mfma_f32_32x32x16_bf16(v1, pa[kc].v, cA1, 0, 0, 0);
        }
      }
    }

    if (kt < 7) { kc0 = kn0; kc1 = kn1; vc0 = vn0; vc1 = vn1; }
    cur ^= 1;
  }

#pragma unroll
  for (int sub = 0; sub < 2; ++sub) {
    float inv = 1.0f / (sub ? lsB : lsA);
    int qrow = sub ? qrowB : qrowA;
    unsigned short* cp = Ctx + ((size_t)g * 512 + qrow) * 64;
#pragma unroll
    for (int dh = 0; dh < 2; ++dh) {
#pragma unroll
      for (int rq = 0; rq < 4; ++rq) {
        float e0 = (sub ? (dh ? cB1[rq * 4 + 0] : cB0[rq * 4 + 0]) : (dh ? cA1[rq * 4 + 0] : cA0[rq * 4 + 0])) * inv;
        float e1 = (sub ? (dh ? cB1[rq * 4 + 1] : cB0[rq * 4 + 1]) : (dh ? cA1[rq * 4 + 1] : cA0[rq * 4 + 1])) * inv;
        float e2 = (sub ? (dh ? cB1[rq * 4 + 2] : cB0[rq * 4 + 2]) : (dh ? cA1[rq * 4 + 2] : cA0[rq * 4 + 2])) * inv;
        float e3 = (sub ? (dh ? cB1[rq * 4 + 3] : cB0[rq * 4 + 3]) : (dh ? cA1[rq * 4 + 3] : cA0[rq * 4 + 3])) * inv;
        int d0 = dh * 32 + rq * 8 + h * 4;
        *(uint2*)(cp + d0) = make_uint2(pkbf(e0, e1), pkbf(e2, e3));
      }
    }
  }
}

// ------------- final FC: out[32][1000] = act[32][262144](bf16) @ Wfc + bfc (split-K) -------------
// KCH=512, grid 512 (2 blocks/CU); thread t owns cols {t, t+512}; 4 k per inner iter
#define KCH 512
__global__ __launch_bounds__(512) void fc_part_kernel(const unsigned short* __restrict__ act,
                                                      const float* __restrict__ Wfc,
                                                      float* __restrict__ part) {
  __shared__ float al[32][256];
  int t = threadIdx.x;
  int kc = blockIdx.x;
  size_t k0 = (size_t)kc * KCH;
  int o1 = t;               // < 1000 always
  int o2 = 512 + t;
  bool a2 = (o2 < O_);
  float acc1[32], acc2[32];
#pragma unroll
  for (int bb = 0; bb < 32; ++bb) { acc1[bb] = 0.0f; acc2[bb] = 0.0f; }
  for (int sub = 0; sub < KCH / 256; ++sub) {
    __syncthreads();
    for (int i = t; i < 32 * 128; i += 512) {
      int bb = i >> 7, kk = (i & 127) * 2;
      ushort2 u = *(const ushort2*)(act + (size_t)bb * 262144 + k0 + sub * 256 + kk);
      al[bb][kk] = bf2f(u.x);
      al[bb][kk + 1] = bf2f(u.y);
    }
    __syncthreads();
    const float* wp = Wfc + (k0 + sub * 256) * O_;
    for (int kk = 0; kk < 256; kk += 4) {
      const float* wr = wp + (size_t)kk * O_;
      float w10 = wr[o1];
      float w11 = wr[O_ + o1];
      float w12 = wr[2 * O_ + o1];
      float w13 = wr[3 * O_ + o1];
      float w20 = a2 ? wr[o2] : 0.0f;
      float w21 = a2 ? wr[O_ + o2] : 0.0f;
      float w22 = a2 ? wr[2 * O_ + o2] : 0.0f;
      float w23 = a2 ? wr[3 * O_ + o2] : 0.0f;
#pragma unroll
      for (int bb = 0; bb < 32; ++bb) {
        f32x4 av = *(const f32x4*)&al[bb][kk];
        acc1[bb] = fmaf(av[0], w10, acc1[bb]);
        acc1[bb] = fmaf(av[1], w11, acc1[bb]);
        acc1[bb] = fmaf(av[2], w12, acc1[bb]);
        acc1[bb] = fmaf(av[3], w13, acc1[bb]);
        acc2[bb] = fmaf(av[0], w20, acc2[bb]);
        acc2[bb] = fmaf(av[1], w21, acc2[bb]);
        acc2[bb] = fmaf(av[2], w22, acc2[bb]);
        acc2[bb] = fmaf(av[3], w23, acc2[bb]);
      }
    }
  }
#pragma unroll
  for (int bb = 0; bb < 32; ++bb) {
    part[((size_t)kc * 32 + bb) * O_ + o1] = acc1[bb];
    if (a2) part[((size_t)kc * 32 + bb) * O_ + o2] = acc2[bb];
  }
}

__global__ void fc_reduce_kernel(const float* __restrict__ part, const float* __restrict__ bfc,
                                 float* __restrict__ out) {
  int o = blockIdx.x * 256 + threadIdx.x;
  int b = blockIdx.y;
  if (o >= O_) return;
  float s = bfc[o];
  for (int c = 0; c < 512; ++c) s += part[((size_t)c * 32 + b) * O_ + o];
  out[(size_t)b * O_ + o] = s;
}

extern "C" void kernel_launch(void* const* d_in, const int* in_sizes, int n_in,
                              void* d_out, int out_size, void* d_ws, size_t ws_size,
                              hipStream_t stream) {
  const int*   x   = (const int*)d_in[0];
  const float* emb = (const float*)d_in[2];
  const float* Wq  = (const float*)d_in[3];
  const float* bq  = (const float*)d_in[4];
  const float* Wk  = (const float*)d_in[5];
  const float* bk  = (const float*)d_in[6];
  const float* Wv  = (const float*)d_in[7];
  const float* bv  = (const float*)d_in[8];
  const float* Wo  = (const float*)d_in[9];
  const float* bo  = (const float*)d_in[10];
  const float* g1  = (const float*)d_in[11];
  const float* bn1 = (const float*)d_in[12];
  const float* W1  = (const float*)d_in[13];
  const float* bf1 = (const float*)d_in[14];
  const float* W2  = (const float*)d_in[15];
  const float* bf2 = (const float*)d_in[16];
  const float* g2  = (const float*)d_in[17];
  const float* bn2 = (const float*)d_in[18];
  const float* Wfc = (const float*)d_in[19];
  const float* bfc = (const float*)d_in[20];
  float* out = (float*)d_out;

  char* ws = (char*)d_ws;
  size_t off = 0;
  auto take = [&](size_t bytes) { char* p = ws + off; off += (bytes + 255) & ~(size_t)255; return p; };
  float*          pe   = (float*)take((size_t)512 * 512 * 4);
  unsigned short* wqkv = (unsigned short*)take((size_t)L_ * 1536 * 512 * 2);
  unsigned short* wot  = (unsigned short*)take((size_t)L_ * 512 * 512 * 2);
  unsigned short* w1t  = (unsigned short*)take((size_t)L_ * 2048 * 512 * 2);
  unsigned short* w2t  = (unsigned short*)take((size_t)L_ * 512 * 2048 * 2);
  unsigned short* xb   = (unsigned short*)take((size_t)M_ * 512 * 2);
  unsigned short* qb   = (unsigned short*)take((size_t)M_ * 512 * 2);
  unsigned short* kb   = (unsigned short*)take((size_t)M_ * 512 * 2);
  unsigned short* vb   = (unsigned short*)take((size_t)M_ * 512 * 2);
  unsigned short* cxb  = (unsigned short*)take((size_t)M_ * 512 * 2);
  unsigned short* hb   = (unsigned short*)take((size_t)M_ * 512 * 2);
  unsigned short* t1   = (unsigned short*)take((size_t)M_ * 512 * 2);
  unsigned short* f1b  = qb;          // alias: q/k/v/cxb region (67 MB contiguous) free during FFN
  float*          part = (float*)qb;  // alias: free after last layer (needs 65.6 MB <= 67 MB)

  pe_kernel<<<1024, 256, 0, stream>>>(pe);
  wconv_kernel<<<dim3(16, 16, L_), 256, 0, stream>>>(Wq, wqkv,          512, 512,  (size_t)1536 * 512);
  wconv_kernel<<<dim3(16, 16, L_), 256, 0, stream>>>(Wk, wqkv + 262144, 512, 512,  (size_t)1536 * 512);
  wconv_kernel<<<dim3(16, 16, L_), 256, 0, stream>>>(Wv, wqkv + 524288, 512, 512,  (size_t)1536 * 512);
  wconv_kernel<<<dim3(16, 16, L_), 256, 0, stream>>>(Wo, wot,           512, 512,  (size_t)512 * 512);
  wconv_kernel<<<dim3(16, 64, L_), 256, 0, stream>>>(W1, w1t,           512, 2048, (size_t)2048 * 512);
  wconv_kernel<<<dim3(64, 16, L_), 256, 0, stream>>>(W2, w2t,           2048, 512, (size_t)512 * 2048);
  embed_kernel<<<M_, 128, 0, stream>>>(x, emb, pe, xb);

  for (int l = 0; l < L_; ++l) {
    // QKV: N=1536 -> nbx=12, grid 1536
    gemm128_kernel<<<1536, 256, 0, stream>>>(
        xb, wqkv + (size_t)l * 1536 * 512,
        bq + l * 512, bk + l * 512, bv + l * 512,
        qb, kb, vb, 512, 1536, 0, 1, 12);
    attn_kernel<<<dim3(2, G_), 256, 0, stream>>>(qb, kb, vb, cxb);
    // O-proj: N=512 -> nbx=4, grid 512
    gemm128_kernel<<<512, 256, 0, stream>>>(
        cxb, wot + (size_t)l * 512 * 512,
        bo + l * 512, nullptr, nullptr,
        t1, nullptr, nullptr, 512, 512, 0, 0, 4);
    addln_kernel<<<M_ / 4, 256, 0, stream>>>(t1, xb, g1 + l * 512, bn1 + l * 512, hb);
    // FF1: N=2048 -> nbx=16, grid 2048
    gemm128_kernel<<<2048, 256, 0, stream>>>(
        hb, w1t + (size_t)l * 2048 * 512,
        bf1 + l * 2048, nullptr, nullptr,
        f1b, nullptr, nullptr, 512, 2048, 1, 0, 16);
    // FF2: N=512, K=2048 -> nbx=4, grid 512
    gemm128_kernel<<<512, 256, 0, stream>>>(
        f1b, w2t + (size_t)l * 512 * 2048,
        bf2 + l * 512, nullptr, nullptr,
        t1, nullptr, nullptr, 2048, 512, 0, 0, 4);
    addln_kernel<<<M_ / 4, 256, 0, stream>>>(t1, hb, g2 + l * 512, bn2 + l * 512, xb);
  }

  fc_part_kernel<<<512, 512, 0, stream>>>(xb, Wfc, part);
  fc_reduce_kernel<<<dim3(4, 32), 256, 0, stream>>>(part, bfc, out);
}